// Round 2
// baseline (1119.979 us; speedup 1.0000x reference)
//
#include <hip/hip_runtime.h>

#define BB 32
#define TT 256
#define NN 128
#define DD 64

#define FMA4(acc, s, v) do { \
    acc.x = __builtin_fmaf((s), (v).x, acc.x); \
    acc.y = __builtin_fmaf((s), (v).y, acc.y); \
    acc.z = __builtin_fmaf((s), (v).z, acc.z); \
    acc.w = __builtin_fmaf((s), (v).w, acc.w); } while (0)

// ---------------------------------------------------------------- K1: build M and LI^T
__global__ __launch_bounds__(256) void k_build(const float* __restrict__ A,
                                               float* __restrict__ Mg,
                                               float* __restrict__ LIt) {
    __shared__ float degs[NN];
    const int b = blockIdx.x;
    const int tid = threadIdx.x;
    const float* Ab = A + b * NN * NN;
    if (tid < NN) {
        float s = 0.f;
        const float4* A4 = (const float4*)(Ab + tid * NN);
        #pragma unroll 4
        for (int j = 0; j < NN / 4; ++j) { float4 v = A4[j]; s += v.x + v.y + v.z + v.w; }
        degs[tid] = s;
    }
    __syncthreads();
    for (int flat = tid; flat < NN * NN; flat += 256) {
        int i = flat >> 7, j = flat & 127;
        float a = Ab[flat];
        float base = -a + ((i == j) ? degs[i] : 0.f);
        Mg[b * NN * NN + flat] = base + ((i == j) ? 1.1f : 0.f);
        LIt[b * NN * NN + j * NN + i] = base + ((i == j) ? 0.1f : 0.f);
    }
}

// ---------------------------------------------------------------- K2: in-place Gauss-Jordan inverse -> invM^T
__global__ __launch_bounds__(256) void k_invert(const float* __restrict__ Mg,
                                                float* __restrict__ invMt) {
    __shared__ float4 sM4s[NN * NN / 4];   // 64 KB
    float* sM = (float*)sM4s;
    float4* sM4 = sM4s;
    const int b = blockIdx.x;
    const int tid = threadIdx.x;
    for (int flat = tid; flat < NN * NN; flat += 256)
        sM[flat] = Mg[b * NN * NN + flat];
    __syncthreads();

    const int jq = tid & 31;      // float4 column index (j0 = 4*jq)
    const int rowoff = tid >> 5;  // 0..7
    const int jb = jq * 4;

    for (int k = 0; k < NN; ++k) {
        float p = 1.0f / sM[k * NN + k];   // read before any write this iter (prev iter ended in barrier)
        __syncthreads();
        if (tid < 32) {                    // scale row k; a[k][k] <- p
            float4 v = sM4[k * 32 + tid];
            int j0 = tid * 4;
            v.x = (j0 + 0 == k) ? p : v.x * p;
            v.y = (j0 + 1 == k) ? p : v.y * p;
            v.z = (j0 + 2 == k) ? p : v.z * p;
            v.w = (j0 + 3 == k) ? p : v.w * p;
            sM4[k * 32 + tid] = v;
        }
        __syncthreads();
        float4 akj = sM4[k * 32 + jq];     // scaled row k, hoisted
        #pragma unroll
        for (int p8 = 0; p8 < 16; ++p8) {
            int i = p8 * 8 + rowoff;       // wave-uniform row within half-wave group
            if (i == k) continue;
            float f = sM[i * NN + k];      // broadcast; read-before-write safe within lockstep half-wave
            float4 v = sM4[i * 32 + jq];
            v.x = ((jb + 0 == k) ? 0.f : v.x) - f * akj.x;
            v.y = ((jb + 1 == k) ? 0.f : v.y) - f * akj.y;
            v.z = ((jb + 2 == k) ? 0.f : v.z) - f * akj.z;
            v.w = ((jb + 3 == k) ? 0.f : v.w) - f * akj.w;
            sM4[i * 32 + jq] = v;
        }
        __syncthreads();
    }
    // write transposed: invMt[k][i] = invM[i][k]
    for (int flat = tid; flat < NN * NN; flat += 256) {
        int kk = flat >> 7, ii = flat & 127;
        invMt[b * NN * NN + flat] = sM[ii * NN + kk];
    }
}

// ---------------------------------------------------------------- K3: Wt[j][i] = sum_k invMt[k][i] * LIt[j][k]
__global__ __launch_bounds__(256) void k_wmat(const float* __restrict__ invMt,
                                              const float* __restrict__ LIt,
                                              float* __restrict__ Wt) {
    __shared__ float4 sLIt4s[16 * NN / 4];  // 8 KB: rows j = jg*16 .. +16
    float* sLIt = (float*)sLIt4s;
    const int bid = blockIdx.x;
    const int b = bid & 31, jg = bid >> 5;
    const int tid = threadIdx.x;
    const float4* LIt4 = (const float4*)(LIt + b * NN * NN + jg * 16 * NN);
    for (int q = tid; q < 512; q += 256) sLIt4s[q] = LIt4[q];
    __syncthreads();

    const int i4 = tid & 31;    // i0 = 4*i4
    const int jl0 = tid >> 5;   // 0..7 ; handles j-local jl0 and jl0+8
    const float4* inv4 = (const float4*)(invMt + b * NN * NN);
    float4 acc0 = {0, 0, 0, 0}, acc1 = {0, 0, 0, 0};
    #pragma unroll 4
    for (int k = 0; k < NN; ++k) {
        float4 m4 = inv4[k * 32 + i4];
        float l0 = sLIt[jl0 * NN + k];
        float l1 = sLIt[(jl0 + 8) * NN + k];
        FMA4(acc0, l0, m4);
        FMA4(acc1, l1, m4);
    }
    float4* Wt4 = (float4*)(Wt + b * NN * NN);
    int j0 = jg * 16 + jl0;
    Wt4[j0 * 32 + i4] = acc0;
    Wt4[(j0 + 8) * 32 + i4] = acc1;
}

// ---------------------------------------------------------------- K4: z[b,t] = invM @ x[b,t]  (written into d_out)
__global__ __launch_bounds__(256) void k_z(const float* __restrict__ invMt,
                                           const float* __restrict__ xs,
                                           float* __restrict__ out) {
    __shared__ float4 sInv4s[NN * NN / 4];  // 64 KB: invMt[k][i]
    __shared__ float4 sX4s[NN * DD / 4];    // 32 KB: x[k][d]
    float4* sInv4 = sInv4s;
    float4* sX4 = sX4s;
    const int bid = blockIdx.x;
    const int b = bid & 31, tc = bid >> 5;  // 8 t-chunks of 32
    const int tid = threadIdx.x;
    const float4* inv4 = (const float4*)(invMt + b * NN * NN);
    for (int q = tid; q < NN * NN / 4; q += 256) sInv4[q] = inv4[q];

    const float4* xs4 = (const float4*)(xs + (size_t)b * TT * NN * DD);
    float4* out4g = (float4*)(out + (size_t)b * TT * NN * DD);
    const int i4 = tid & 31;   // i0 = 4*i4
    const int dg = tid >> 5;   // d0 = 8*dg

    float4 xr[8];
    {
        int t = tc * 32;
        #pragma unroll
        for (int r = 0; r < 8; ++r) xr[r] = xs4[(size_t)t * (NN * DD / 4) + r * 256 + tid];
    }
    for (int tt = 0; tt < 32; ++tt) {
        int t = tc * 32 + tt;
        __syncthreads();                       // sX free (also covers sInv staging on first iter)
        #pragma unroll
        for (int r = 0; r < 8; ++r) sX4[r * 256 + tid] = xr[r];
        __syncthreads();
        if (tt < 31) {
            #pragma unroll
            for (int r = 0; r < 8; ++r) xr[r] = xs4[(size_t)(t + 1) * (NN * DD / 4) + r * 256 + tid];
        }
        float4 acc[4][2];
        #pragma unroll
        for (int r = 0; r < 4; ++r) { acc[r][0] = float4{0,0,0,0}; acc[r][1] = float4{0,0,0,0}; }
        #pragma unroll 2
        for (int k = 0; k < NN; ++k) {
            float4 m4 = sInv4[k * 32 + i4];
            float4 xa = sX4[k * 16 + dg * 2];
            float4 xb = sX4[k * 16 + dg * 2 + 1];
            FMA4(acc[0][0], m4.x, xa); FMA4(acc[0][1], m4.x, xb);
            FMA4(acc[1][0], m4.y, xa); FMA4(acc[1][1], m4.y, xb);
            FMA4(acc[2][0], m4.z, xa); FMA4(acc[2][1], m4.z, xb);
            FMA4(acc[3][0], m4.w, xa); FMA4(acc[3][1], m4.w, xb);
        }
        #pragma unroll
        for (int r = 0; r < 4; ++r) {
            out4g[(size_t)t * (NN * DD / 4) + (i4 * 4 + r) * 16 + dg * 2]     = acc[r][0];
            out4g[(size_t)t * (NN * DD / 4) + (i4 * 4 + r) * 16 + dg * 2 + 1] = acc[r][1];
        }
    }
}

// ---------------------------------------------------------------- K5: scan y_t = W y_{t-1} + z_t (in-place over z in d_out)
__global__ __launch_bounds__(256) void k_scan(const float* __restrict__ Wt,
                                              float* __restrict__ out) {
    __shared__ float4 yl4[NN * 8 / 4];        // y[j][8]   4 KB
    __shared__ float4 red4[4 * NN * 8 / 4];   // [w][i][8] 16 KB
    const int bid = blockIdx.x;
    const int b = bid & 31, dc = bid >> 5;    // dc 0..7 ; same-b blocks share an XCD
    const int tid = threadIdx.x;
    const int w = tid >> 6, q = tid & 63;

    // W in registers: thread holds W[i][j] for i in {2q,2q+1}, j in [32w,32w+32)
    float2 wv[32];
    const float2* Wt2 = (const float2*)(Wt + b * NN * NN + (w * 32) * NN);
    #pragma unroll
    for (int jj = 0; jj < 32; ++jj) wv[jj] = Wt2[jj * 64 + q];

    yl4[tid] = float4{0, 0, 0, 0};            // y0 = 0 (256 float4 = 1024 floats)
    float4* outbase4 = (float4*)(out + (size_t)b * TT * NN * DD);
    const int oi = tid >> 1, hf = tid & 1;
    float4 zp = outbase4[oi * 16 + dc * 2 + hf];   // prefetch z_0
    __syncthreads();

    for (int t = 0; t < TT; ++t) {
        float4 a00 = {0,0,0,0}, a01 = {0,0,0,0}, a10 = {0,0,0,0}, a11 = {0,0,0,0};
        #pragma unroll
        for (int jj = 0; jj < 32; ++jj) {
            int j = w * 32 + jj;
            float4 ya = yl4[j * 2];
            float4 yb = yl4[j * 2 + 1];
            float wa = wv[jj].x, wb = wv[jj].y;
            FMA4(a00, wa, ya); FMA4(a01, wa, yb);
            FMA4(a10, wb, ya); FMA4(a11, wb, yb);
        }
        __syncthreads();
        red4[w * 256 + q * 4 + 0] = a00;
        red4[w * 256 + q * 4 + 1] = a01;
        red4[w * 256 + q * 4 + 2] = a10;
        red4[w * 256 + q * 4 + 3] = a11;
        __syncthreads();
        float4 s0 = red4[      oi * 2 + hf];
        float4 s1 = red4[256 + oi * 2 + hf];
        float4 s2 = red4[512 + oi * 2 + hf];
        float4 s3 = red4[768 + oi * 2 + hf];
        float4 s;
        s.x = (s0.x + s1.x) + (s2.x + s3.x) + zp.x;
        s.y = (s0.y + s1.y) + (s2.y + s3.y) + zp.y;
        s.z = (s0.z + s1.z) + (s2.z + s3.z) + zp.z;
        s.w = (s0.w + s1.w) + (s2.w + s3.w) + zp.w;
        yl4[oi * 2 + hf] = s;
        outbase4[(size_t)t * (NN * DD / 4) + oi * 16 + dc * 2 + hf] = s;
        if (t + 1 < TT) zp = outbase4[(size_t)(t + 1) * (NN * DD / 4) + oi * 16 + dc * 2 + hf];
        __syncthreads();
    }
}

// ----------------------------------------------------------------
extern "C" void kernel_launch(void* const* d_in, const int* in_sizes, int n_in,
                              void* d_out, int out_size, void* d_ws, size_t ws_size,
                              hipStream_t stream) {
    const float* xs = (const float*)d_in[0];   // [32,256,128,64]
    const float* A  = (const float*)d_in[1];   // [32,128,128]
    float* out = (float*)d_out;                // [32,256,128,64]
    float* ws = (float*)d_ws;                  // needs 8 MB

    float* Mg    = ws;                          // [32][128][128]
    float* invMt = ws + 1 * BB * NN * NN;       // invM^T per batch
    float* LIt   = ws + 2 * BB * NN * NN;       // LI^T per batch
    float* Wtm   = ws + 3 * BB * NN * NN;       // W^T per batch

    k_build <<<BB, 256, 0, stream>>>(A, Mg, LIt);
    k_invert<<<BB, 256, 0, stream>>>(Mg, invMt);
    k_wmat  <<<256, 256, 0, stream>>>(invMt, LIt, Wtm);
    k_z     <<<256, 256, 0, stream>>>(invMt, xs, out);
    k_scan  <<<256, 256, 0, stream>>>(Wtm, out);
}

// Round 3
// 1117.264 us; speedup vs baseline: 1.0024x; 1.0024x over previous
//
#include <hip/hip_runtime.h>

#define BB 32
#define TT 256
#define NN 128
#define DD 64

#define FMA4(acc, s, v) do { \
    acc.x = __builtin_fmaf((s), (v).x, acc.x); \
    acc.y = __builtin_fmaf((s), (v).y, acc.y); \
    acc.z = __builtin_fmaf((s), (v).z, acc.z); \
    acc.w = __builtin_fmaf((s), (v).w, acc.w); } while (0)

// ---------------------------------------------------------------- K1: build M and LI^T
__global__ __launch_bounds__(256) void k_build(const float* __restrict__ A,
                                               float* __restrict__ Mg,
                                               float* __restrict__ LIt) {
    __shared__ float degs[NN];
    const int b = blockIdx.x;
    const int tid = threadIdx.x;
    const float* Ab = A + b * NN * NN;
    if (tid < NN) {
        float s = 0.f;
        const float4* A4 = (const float4*)(Ab + tid * NN);
        #pragma unroll 4
        for (int j = 0; j < NN / 4; ++j) { float4 v = A4[j]; s += v.x + v.y + v.z + v.w; }
        degs[tid] = s;
    }
    __syncthreads();
    for (int flat = tid; flat < NN * NN; flat += 256) {
        int i = flat >> 7, j = flat & 127;
        float a = Ab[flat];
        float base = -a + ((i == j) ? degs[i] : 0.f);
        Mg[b * NN * NN + flat] = base + ((i == j) ? 1.1f : 0.f);
        LIt[b * NN * NN + j * NN + i] = base + ((i == j) ? 0.1f : 0.f);
    }
}

// ---------------------------------------------------------------- K2: in-place Gauss-Jordan inverse -> invM^T
__global__ __launch_bounds__(256) void k_invert(const float* __restrict__ Mg,
                                                float* __restrict__ invMt) {
    __shared__ float4 sM4s[NN * NN / 4];   // 64 KB
    float* sM = (float*)sM4s;
    float4* sM4 = sM4s;
    const int b = blockIdx.x;
    const int tid = threadIdx.x;
    for (int flat = tid; flat < NN * NN; flat += 256)
        sM[flat] = Mg[b * NN * NN + flat];
    __syncthreads();

    const int jq = tid & 31;      // float4 column index (j0 = 4*jq)
    const int rowoff = tid >> 5;  // 0..7
    const int jb = jq * 4;

    for (int k = 0; k < NN; ++k) {
        float p = 1.0f / sM[k * NN + k];   // read before any write this iter (prev iter ended in barrier)
        __syncthreads();
        if (tid < 32) {                    // scale row k; a[k][k] <- p
            float4 v = sM4[k * 32 + tid];
            int j0 = tid * 4;
            v.x = (j0 + 0 == k) ? p : v.x * p;
            v.y = (j0 + 1 == k) ? p : v.y * p;
            v.z = (j0 + 2 == k) ? p : v.z * p;
            v.w = (j0 + 3 == k) ? p : v.w * p;
            sM4[k * 32 + tid] = v;
        }
        __syncthreads();
        float4 akj = sM4[k * 32 + jq];     // scaled row k, hoisted
        #pragma unroll
        for (int p8 = 0; p8 < 16; ++p8) {
            int i = p8 * 8 + rowoff;       // wave-uniform row within half-wave group
            if (i == k) continue;
            float f = sM[i * NN + k];      // broadcast; read-before-write safe within lockstep half-wave
            float4 v = sM4[i * 32 + jq];
            v.x = ((jb + 0 == k) ? 0.f : v.x) - f * akj.x;
            v.y = ((jb + 1 == k) ? 0.f : v.y) - f * akj.y;
            v.z = ((jb + 2 == k) ? 0.f : v.z) - f * akj.z;
            v.w = ((jb + 3 == k) ? 0.f : v.w) - f * akj.w;
            sM4[i * 32 + jq] = v;
        }
        __syncthreads();
    }
    // write transposed: invMt[k][i] = invM[i][k]
    for (int flat = tid; flat < NN * NN; flat += 256) {
        int kk = flat >> 7, ii = flat & 127;
        invMt[b * NN * NN + flat] = sM[ii * NN + kk];
    }
}

// ---------------------------------------------------------------- K3: Wt[j][i] = sum_k invMt[k][i] * LIt[j][k]
__global__ __launch_bounds__(256) void k_wmat(const float* __restrict__ invMt,
                                              const float* __restrict__ LIt,
                                              float* __restrict__ Wt) {
    __shared__ float4 sLIt4s[16 * NN / 4];  // 8 KB: rows j = jg*16 .. +16
    float* sLIt = (float*)sLIt4s;
    const int bid = blockIdx.x;
    const int b = bid & 31, jg = bid >> 5;
    const int tid = threadIdx.x;
    const float4* LIt4 = (const float4*)(LIt + b * NN * NN + jg * 16 * NN);
    for (int q = tid; q < 512; q += 256) sLIt4s[q] = LIt4[q];
    __syncthreads();

    const int i4 = tid & 31;    // i0 = 4*i4
    const int jl0 = tid >> 5;   // 0..7 ; handles j-local jl0 and jl0+8
    const float4* inv4 = (const float4*)(invMt + b * NN * NN);
    float4 acc0 = {0, 0, 0, 0}, acc1 = {0, 0, 0, 0};
    #pragma unroll 4
    for (int k = 0; k < NN; ++k) {
        float4 m4 = inv4[k * 32 + i4];
        float l0 = sLIt[jl0 * NN + k];
        float l1 = sLIt[(jl0 + 8) * NN + k];
        FMA4(acc0, l0, m4);
        FMA4(acc1, l1, m4);
    }
    float4* Wt4 = (float4*)(Wt + b * NN * NN);
    int j0 = jg * 16 + jl0;
    Wt4[j0 * 32 + i4] = acc0;
    Wt4[(j0 + 8) * 32 + i4] = acc1;
}

// ---------------------------------------------------------------- K4: z[b,t] = invM @ x[b,t]  (written into d_out)
__global__ __launch_bounds__(256) void k_z(const float* __restrict__ invMt,
                                           const float* __restrict__ xs,
                                           float* __restrict__ out) {
    __shared__ float4 sInv4s[NN * NN / 4];  // 64 KB: invMt[k][i]
    __shared__ float4 sX4s[NN * DD / 4];    // 32 KB: x[k][d]
    float4* sInv4 = sInv4s;
    float4* sX4 = sX4s;
    const int bid = blockIdx.x;
    const int b = bid & 31, tc = bid >> 5;  // 8 t-chunks of 32
    const int tid = threadIdx.x;
    const float4* inv4 = (const float4*)(invMt + b * NN * NN);
    for (int q = tid; q < NN * NN / 4; q += 256) sInv4[q] = inv4[q];

    const float4* xs4 = (const float4*)(xs + (size_t)b * TT * NN * DD);
    float4* out4g = (float4*)(out + (size_t)b * TT * NN * DD);
    const int i4 = tid & 31;   // i0 = 4*i4
    const int dg = tid >> 5;   // d0 = 8*dg

    float4 xr[8];
    {
        int t = tc * 32;
        #pragma unroll
        for (int r = 0; r < 8; ++r) xr[r] = xs4[(size_t)t * (NN * DD / 4) + r * 256 + tid];
    }
    for (int tt = 0; tt < 32; ++tt) {
        int t = tc * 32 + tt;
        __syncthreads();                       // sX free (also covers sInv staging on first iter)
        #pragma unroll
        for (int r = 0; r < 8; ++r) sX4[r * 256 + tid] = xr[r];
        __syncthreads();
        if (tt < 31) {
            #pragma unroll
            for (int r = 0; r < 8; ++r) xr[r] = xs4[(size_t)(t + 1) * (NN * DD / 4) + r * 256 + tid];
        }
        float4 acc[4][2];
        #pragma unroll
        for (int r = 0; r < 4; ++r) { acc[r][0] = float4{0,0,0,0}; acc[r][1] = float4{0,0,0,0}; }
        #pragma unroll 2
        for (int k = 0; k < NN; ++k) {
            float4 m4 = sInv4[k * 32 + i4];
            float4 xa = sX4[k * 16 + dg * 2];
            float4 xb = sX4[k * 16 + dg * 2 + 1];
            FMA4(acc[0][0], m4.x, xa); FMA4(acc[0][1], m4.x, xb);
            FMA4(acc[1][0], m4.y, xa); FMA4(acc[1][1], m4.y, xb);
            FMA4(acc[2][0], m4.z, xa); FMA4(acc[2][1], m4.z, xb);
            FMA4(acc[3][0], m4.w, xa); FMA4(acc[3][1], m4.w, xb);
        }
        #pragma unroll
        for (int r = 0; r < 4; ++r) {
            out4g[(size_t)t * (NN * DD / 4) + (i4 * 4 + r) * 16 + dg * 2]     = acc[r][0];
            out4g[(size_t)t * (NN * DD / 4) + (i4 * 4 + r) * 16 + dg * 2 + 1] = acc[r][1];
        }
    }
}

// ---------------------------------------------------------------- K5: scan y_t = W y_{t-1} + z_t (in-place over z in d_out)
__global__ __launch_bounds__(256) void k_scan(const float* __restrict__ Wt,
                                              float* __restrict__ out) {
    __shared__ float4 yl4[NN * 8 / 4];        // y[j][8]   4 KB
    __shared__ float4 red4[4 * NN * 8 / 4];   // [w][i][8] 16 KB
    const int bid = blockIdx.x;
    const int b = bid & 31, dc = bid >> 5;    // dc 0..7 ; same-b blocks share an XCD
    const int tid = threadIdx.x;
    const int w = tid >> 6, q = tid & 63;

    // W in registers: thread holds W[i][j] for i in {2q,2q+1}, j in [32w,32w+32)
    float2 wv[32];
    const float2* Wt2 = (const float2*)(Wt + b * NN * NN + (w * 32) * NN);
    #pragma unroll
    for (int jj = 0; jj < 32; ++jj) wv[jj] = Wt2[jj * 64 + q];

    yl4[tid] = float4{0, 0, 0, 0};            // y0 = 0 (256 float4 = 1024 floats)
    float4* outbase4 = (float4*)(out + (size_t)b * TT * NN * DD);
    const int oi = tid >> 1, hf = tid & 1;
    float4 zp = outbase4[oi * 16 + dc * 2 + hf];   // prefetch z_0
    __syncthreads();

    for (int t = 0; t < TT; ++t) {
        float4 a00 = {0,0,0,0}, a01 = {0,0,0,0}, a10 = {0,0,0,0}, a11 = {0,0,0,0};
        #pragma unroll
        for (int jj = 0; jj < 32; ++jj) {
            int j = w * 32 + jj;
            float4 ya = yl4[j * 2];
            float4 yb = yl4[j * 2 + 1];
            float wa = wv[jj].x, wb = wv[jj].y;
            FMA4(a00, wa, ya); FMA4(a01, wa, yb);
            FMA4(a10, wb, ya); FMA4(a11, wb, yb);
        }
        __syncthreads();
        red4[w * 256 + q * 4 + 0] = a00;
        red4[w * 256 + q * 4 + 1] = a01;
        red4[w * 256 + q * 4 + 2] = a10;
        red4[w * 256 + q * 4 + 3] = a11;
        __syncthreads();
        float4 s0 = red4[      oi * 2 + hf];
        float4 s1 = red4[256 + oi * 2 + hf];
        float4 s2 = red4[512 + oi * 2 + hf];
        float4 s3 = red4[768 + oi * 2 + hf];
        float4 s;
        s.x = (s0.x + s1.x) + (s2.x + s3.x) + zp.x;
        s.y = (s0.y + s1.y) + (s2.y + s3.y) + zp.y;
        s.z = (s0.z + s1.z) + (s2.z + s3.z) + zp.z;
        s.w = (s0.w + s1.w) + (s2.w + s3.w) + zp.w;
        yl4[oi * 2 + hf] = s;
        outbase4[(size_t)t * (NN * DD / 4) + oi * 16 + dc * 2 + hf] = s;
        if (t + 1 < TT) zp = outbase4[(size_t)(t + 1) * (NN * DD / 4) + oi * 16 + dc * 2 + hf];
        __syncthreads();
    }
}

// ----------------------------------------------------------------
extern "C" void kernel_launch(void* const* d_in, const int* in_sizes, int n_in,
                              void* d_out, int out_size, void* d_ws, size_t ws_size,
                              hipStream_t stream) {
    const float* xs = (const float*)d_in[0];   // [32,256,128,64]
    const float* A  = (const float*)d_in[1];   // [32,128,128]
    float* out = (float*)d_out;                // [32,256,128,64]
    float* ws = (float*)d_ws;                  // needs 8 MB

    float* Mg    = ws;                          // [32][128][128]
    float* invMt = ws + 1 * BB * NN * NN;       // invM^T per batch
    float* LIt   = ws + 2 * BB * NN * NN;       // LI^T per batch
    float* Wtm   = ws + 3 * BB * NN * NN;       // W^T per batch

    k_build <<<BB, 256, 0, stream>>>(A, Mg, LIt);
    k_invert<<<BB, 256, 0, stream>>>(Mg, invMt);
    k_wmat  <<<256, 256, 0, stream>>>(invMt, LIt, Wtm);
    k_z     <<<256, 256, 0, stream>>>(invMt, xs, out);
    k_scan  <<<256, 256, 0, stream>>>(Wtm, out);
}

// Round 4
// 658.861 us; speedup vs baseline: 1.6999x; 1.6958x over previous
//
#include <hip/hip_runtime.h>

#define BB 32
#define TT 256
#define NN 128
#define DD 64
#define LSTR 132   // padded column stride in halves: 264B = 66 dwords ≡ 2 (mod 32) -> 2-way (free) bank pattern

typedef _Float16 f16x4 __attribute__((ext_vector_type(4)));
typedef _Float16 f16x8 __attribute__((ext_vector_type(8)));
typedef float    f32x16 __attribute__((ext_vector_type(16)));

// barrier that drains only LDS (lgkmcnt) — keeps global prefetch loads / stores in flight
#define LBAR() do { asm volatile("s_waitcnt lgkmcnt(0)" ::: "memory"); \
                    __builtin_amdgcn_s_barrier(); } while (0)

// ---------------------------------------------------------------- K1: build M and LI^T
__global__ __launch_bounds__(256) void k_build(const float* __restrict__ A,
                                               float* __restrict__ Mg,
                                               float* __restrict__ LIt) {
    __shared__ float degs[NN];
    const int b = blockIdx.x;
    const int tid = threadIdx.x;
    const float* Ab = A + b * NN * NN;
    if (tid < NN) {
        float s = 0.f;
        const float4* A4 = (const float4*)(Ab + tid * NN);
        #pragma unroll 4
        for (int j = 0; j < NN / 4; ++j) { float4 v = A4[j]; s += v.x + v.y + v.z + v.w; }
        degs[tid] = s;
    }
    __syncthreads();
    for (int flat = tid; flat < NN * NN; flat += 256) {
        int i = flat >> 7, j = flat & 127;
        float a = Ab[flat];
        float base = -a + ((i == j) ? degs[i] : 0.f);
        Mg[b * NN * NN + flat] = base + ((i == j) ? 1.1f : 0.f);
        LIt[b * NN * NN + j * NN + i] = base + ((i == j) ? 0.1f : 0.f);
    }
}

// ---------------------------------------------------------------- K2: in-place Gauss-Jordan inverse -> invM^T
__global__ __launch_bounds__(256) void k_invert(const float* __restrict__ Mg,
                                                float* __restrict__ invMt) {
    __shared__ float4 sM4s[NN * NN / 4];   // 64 KB
    float* sM = (float*)sM4s;
    float4* sM4 = sM4s;
    const int b = blockIdx.x;
    const int tid = threadIdx.x;
    for (int flat = tid; flat < NN * NN; flat += 256)
        sM[flat] = Mg[b * NN * NN + flat];
    __syncthreads();

    const int jq = tid & 31;      // float4 column index (j0 = 4*jq)
    const int rowoff = tid >> 5;  // 0..7
    const int jb = jq * 4;

    for (int k = 0; k < NN; ++k) {
        float p = 1.0f / sM[k * NN + k];   // read before any write this iter (prev iter ended in barrier)
        __syncthreads();
        if (tid < 32) {                    // scale row k; a[k][k] <- p
            float4 v = sM4[k * 32 + tid];
            int j0 = tid * 4;
            v.x = (j0 + 0 == k) ? p : v.x * p;
            v.y = (j0 + 1 == k) ? p : v.y * p;
            v.z = (j0 + 2 == k) ? p : v.z * p;
            v.w = (j0 + 3 == k) ? p : v.w * p;
            sM4[k * 32 + tid] = v;
        }
        __syncthreads();
        float4 akj = sM4[k * 32 + jq];     // scaled row k, hoisted
        #pragma unroll
        for (int p8 = 0; p8 < 16; ++p8) {
            int i = p8 * 8 + rowoff;       // wave-uniform row within half-wave group
            if (i == k) continue;
            float f = sM[i * NN + k];      // broadcast; read-before-write safe within lockstep half-wave
            float4 v = sM4[i * 32 + jq];
            v.x = ((jb + 0 == k) ? 0.f : v.x) - f * akj.x;
            v.y = ((jb + 1 == k) ? 0.f : v.y) - f * akj.y;
            v.z = ((jb + 2 == k) ? 0.f : v.z) - f * akj.z;
            v.w = ((jb + 3 == k) ? 0.f : v.w) - f * akj.w;
            sM4[i * 32 + jq] = v;
        }
        __syncthreads();
    }
    // write transposed: invMt[k][i] = invM[i][k]
    for (int flat = tid; flat < NN * NN; flat += 256) {
        int kk = flat >> 7, ii = flat & 127;
        invMt[b * NN * NN + flat] = sM[ii * NN + kk];
    }
}

// ---------------------------------------------------------------- K3: fused scan via MFMA
// per block: batch b, d-half dc (32 cols). 4 waves = 4 M-blocks of 32 rows.
// per step: u = LI*y + x  (phase A);  y = invM*u  (phase B); y,u shared via fp16 LDS columns.
// A operands (LI, invM) pre-split hi + 2^-12*lo' in fp16 registers (lo' scaled x4096:
// stays fp16-normal; systematic matrix error ~2^-24, which matters since (I-W)^-1 = M amplifies ~130x).
// B operands (y,u) single fp16: per-step 2^-12 quantization is random -> random-walk ~5e-4 total.
// k-mapping kappa(h,e)=8h+e used for BOTH A and B: any consistent bijection gives a correct contraction.
__global__ __launch_bounds__(256, 1) void k_fused(const float* __restrict__ LIt,
                                                  const float* __restrict__ invMt,
                                                  const float* __restrict__ xs,
                                                  float* __restrict__ out) {
    __shared__ __align__(16) _Float16 uL[32][LSTR];  // uL[c][row], column-major, padded
    __shared__ __align__(16) _Float16 yL[32][LSTR];

    const int bid = blockIdx.x;
    const int b = bid >> 1, dc = bid & 1;
    const int tid = threadIdx.x;
    const int w = tid >> 6;        // M-block (rows 32w..32w+31)
    const int l = tid & 63;
    const int c = l & 31;          // column (d-local) / A-row-local
    const int h = l >> 5;          // lane half -> k-group

    // zero y_0
    for (int q = tid; q < 32 * LSTR / 2; q += 256) ((unsigned int*)yL)[q] = 0u;

    // ---- preload A-fragments: LI and invM rows R=32w+c, hi/lo split
    f16x8 LHi[8], LLo[8], VHi[8], VLo[8];
    {
        const float* LIb = LIt + b * NN * NN;
        const float* Vb  = invMt + b * NN * NN;
        const int R = w * 32 + c;
        #pragma unroll
        for (int ks = 0; ks < 8; ++ks) {
            #pragma unroll
            for (int e = 0; e < 8; ++e) {
                int k = ks * 16 + h * 8 + e;            // kappa(h,e)=8h+e
                float f = LIb[k * NN + R];              // LIt[k][R] = LI[R][k]; lanes coalesced over R
                _Float16 fh = (_Float16)f;
                LHi[ks][e] = fh;
                LLo[ks][e] = (_Float16)((f - (float)fh) * 4096.0f);
                float g = Vb[k * NN + R];
                _Float16 gh = (_Float16)g;
                VHi[ks][e] = gh;
                VLo[ks][e] = (_Float16)((g - (float)gh) * 4096.0f);
            }
        }
    }

    const size_t tstr = (size_t)NN * DD;
    const size_t xoff = (size_t)b * TT * tstr + (size_t)dc * 32 + c;  // + t*tstr + Ri*DD
    const int ldsrow = w * 32 + h * 4;    // base LDS row this lane writes (g adds 8g)

    LBAR();   // y_0 visible

    for (int t = 0; t < TT; ++t) {
        // issue x loads for this t (consumed at end of phase A; latency hidden under MFMAs)
        float xn[16];
        #pragma unroll
        for (int i = 0; i < 16; ++i) {
            int Ri = w * 32 + (i & 3) + 8 * (i >> 2) + 4 * h;   // D-layout row
            xn[i] = xs[xoff + (size_t)t * tstr + (size_t)Ri * DD];
        }

        // ---- phase A: u = LI*y + x
        f32x16 a0, a1;
        #pragma unroll
        for (int i = 0; i < 16; ++i) { a0[i] = 0.f; a1[i] = 0.f; }
        #pragma unroll
        for (int ks = 0; ks < 8; ++ks) {
            f16x4 p0 = *(const f16x4*)&yL[c][ks * 16 + h * 8];
            f16x4 p1 = *(const f16x4*)&yL[c][ks * 16 + h * 8 + 4];
            f16x8 bf = __builtin_shufflevector(p0, p1, 0, 1, 2, 3, 4, 5, 6, 7);
            a0 = __builtin_amdgcn_mfma_f32_32x32x16_f16(LHi[ks], bf, a0, 0, 0, 0);
            a1 = __builtin_amdgcn_mfma_f32_32x32x16_f16(LLo[ks], bf, a1, 0, 0, 0);
        }
        float u[16];
        #pragma unroll
        for (int i = 0; i < 16; ++i)
            u[i] = __builtin_fmaf(a1[i], (1.0f / 4096.0f), a0[i]) + xn[i];
        #pragma unroll
        for (int g = 0; g < 4; ++g) {      // rows 32w + 8g + 4h + {0..3}
            f16x4 p;
            p[0] = (_Float16)u[g * 4 + 0]; p[1] = (_Float16)u[g * 4 + 1];
            p[2] = (_Float16)u[g * 4 + 2]; p[3] = (_Float16)u[g * 4 + 3];
            *(f16x4*)&uL[c][ldsrow + g * 8] = p;
        }
        LBAR();

        // ---- phase B: y = invM*u
        #pragma unroll
        for (int i = 0; i < 16; ++i) { a0[i] = 0.f; a1[i] = 0.f; }
        #pragma unroll
        for (int ks = 0; ks < 8; ++ks) {
            f16x4 p0 = *(const f16x4*)&uL[c][ks * 16 + h * 8];
            f16x4 p1 = *(const f16x4*)&uL[c][ks * 16 + h * 8 + 4];
            f16x8 bf = __builtin_shufflevector(p0, p1, 0, 1, 2, 3, 4, 5, 6, 7);
            a0 = __builtin_amdgcn_mfma_f32_32x32x16_f16(VHi[ks], bf, a0, 0, 0, 0);
            a1 = __builtin_amdgcn_mfma_f32_32x32x16_f16(VLo[ks], bf, a1, 0, 0, 0);
        }
        float y[16];
        #pragma unroll
        for (int i = 0; i < 16; ++i)
            y[i] = __builtin_fmaf(a1[i], (1.0f / 4096.0f), a0[i]);

        // store y_t (fire-and-forget; vmcnt not drained at barrier)
        #pragma unroll
        for (int i = 0; i < 16; ++i) {
            int Ri = w * 32 + (i & 3) + 8 * (i >> 2) + 4 * h;
            out[xoff + (size_t)t * tstr + (size_t)Ri * DD] = y[i];
        }
        // publish y_t as fp16 for next step
        #pragma unroll
        for (int g = 0; g < 4; ++g) {
            f16x4 p;
            p[0] = (_Float16)y[g * 4 + 0]; p[1] = (_Float16)y[g * 4 + 1];
            p[2] = (_Float16)y[g * 4 + 2]; p[3] = (_Float16)y[g * 4 + 3];
            *(f16x4*)&yL[c][ldsrow + g * 8] = p;
        }
        LBAR();
    }
}

// ----------------------------------------------------------------
extern "C" void kernel_launch(void* const* d_in, const int* in_sizes, int n_in,
                              void* d_out, int out_size, void* d_ws, size_t ws_size,
                              hipStream_t stream) {
    const float* xs = (const float*)d_in[0];   // [32,256,128,64]
    const float* A  = (const float*)d_in[1];   // [32,128,128]
    float* out = (float*)d_out;                // [32,256,128,64]
    float* ws = (float*)d_ws;                  // needs 6 MB

    float* Mg    = ws;                          // [32][128][128]
    float* invMt = ws + 1 * BB * NN * NN;       // invM^T per batch
    float* LIt   = ws + 2 * BB * NN * NN;       // LI^T per batch

    k_build <<<BB, 256, 0, stream>>>(A, Mg, LIt);
    k_invert<<<BB, 256, 0, stream>>>(Mg, invMt);
    k_fused <<<BB * 2, 256, 0, stream>>>(LIt, invMt, xs, out);
}

// Round 5
// 346.227 us; speedup vs baseline: 3.2348x; 1.9030x over previous
//
#include <hip/hip_runtime.h>

#define BB 32
#define TT 256
#define NN 128
#define DD 64
#define KSTR 136   // yL/uL column stride in halves: 272B=68 dwords -> (4cl+4h) bank quads, uniform 8/quad

typedef _Float16 f16x4 __attribute__((ext_vector_type(4)));
typedef _Float16 f16x8 __attribute__((ext_vector_type(8)));
typedef float    f32x4v __attribute__((ext_vector_type(4)));

#define FMA4(acc, s, v) do { \
    acc.x = __builtin_fmaf((s), (v).x, acc.x); \
    acc.y = __builtin_fmaf((s), (v).y, acc.y); \
    acc.z = __builtin_fmaf((s), (v).z, acc.z); \
    acc.w = __builtin_fmaf((s), (v).w, acc.w); } while (0)

// barrier that drains only LDS (lgkmcnt) — keeps global prefetch loads / stores in flight
#define LBAR() do { asm volatile("s_waitcnt lgkmcnt(0)" ::: "memory"); \
                    __builtin_amdgcn_s_barrier(); } while (0)

// ---------------------------------------------------------------- K1: build M and LI^T
__global__ __launch_bounds__(256) void k_build(const float* __restrict__ A,
                                               float* __restrict__ Mg,
                                               float* __restrict__ LIt) {
    __shared__ float degs[NN];
    const int b = blockIdx.x;
    const int tid = threadIdx.x;
    const float* Ab = A + b * NN * NN;
    if (tid < NN) {
        float s = 0.f;
        const float4* A4 = (const float4*)(Ab + tid * NN);
        #pragma unroll 4
        for (int j = 0; j < NN / 4; ++j) { float4 v = A4[j]; s += v.x + v.y + v.z + v.w; }
        degs[tid] = s;
    }
    __syncthreads();
    for (int flat = tid; flat < NN * NN; flat += 256) {
        int i = flat >> 7, j = flat & 127;
        float a = Ab[flat];
        float base = -a + ((i == j) ? degs[i] : 0.f);
        Mg[b * NN * NN + flat] = base + ((i == j) ? 1.1f : 0.f);
        LIt[b * NN * NN + j * NN + i] = base + ((i == j) ? 0.1f : 0.f);
    }
}

// ---------------------------------------------------------------- K2: blocked Gauss-Jordan inverse -> invM^T
// panel width 16: 16 latency-bound ministeps on a 128x16 panel, then one rank-16
// throughput update of the other 112 columns. Identity correction of the composed
// transform folds into seeding panel-row accumulators with 0 (old value cancels).
__global__ __launch_bounds__(256) void k_invert(const float* __restrict__ Mg,
                                                float* __restrict__ invMt) {
    __shared__ __align__(16) float sM[NN][132];   // 66 KB, stride 132 dwords
    __shared__ __align__(16) float rB[16][NN];    // 8 KB staged row-block (old values)
    const int b = blockIdx.x;
    const int tid = threadIdx.x;
    for (int flat = tid; flat < NN * NN; flat += 256)
        sM[flat >> 7][flat & 127] = Mg[b * NN * NN + flat];
    __syncthreads();

    const int jl = tid & 15;     // panel column (phase 1)
    const int rg = tid >> 4;     // row group: rows rg*8..rg*8+8 (phase 1)
    const int qq = tid & 31;     // column quad (phase 2)
    const int rh = tid >> 5;     // row half-set: rows rh*16..rh*16+16 (phase 2)

    for (int pk = 0; pk < 8; ++pk) {
        const int K0 = pk << 4;
        // ---- phase 1: mini-GJ restricted to panel columns [K0, K0+16)
        for (int kl = 0; kl < 16; ++kl) {
            const int k = K0 + kl;
            const float pv  = sM[k][K0 + kl];
            const float akj = sM[k][K0 + jl];
            float f[8], v[8];
            #pragma unroll
            for (int r = 0; r < 8; ++r) {
                f[r] = sM[rg * 8 + r][K0 + kl];
                v[r] = sM[rg * 8 + r][K0 + jl];
            }
            __syncthreads();                  // all old values read before any write
            const float p = 1.0f / pv;
            const float pak = p * akj;
            #pragma unroll
            for (int r = 0; r < 8; ++r) {
                const int i = rg * 8 + r;
                float nv;
                if (i == k) nv = (jl == kl) ? p : akj * p;
                else        nv = (jl == kl) ? -f[r] * p : v[r] - f[r] * pak;
                sM[i][K0 + jl] = nv;
            }
            __syncthreads();
        }
        // ---- stage old row-block R = sM[K0..K0+16)[all cols]
        for (int q = tid; q < 16 * NN / 4; q += 256) {
            const int m = q >> 5, j4 = (q & 31) << 2;
            *(float4*)&rB[m][j4] = *(float4*)&sM[K0 + m][j4];
        }
        __syncthreads();
        // ---- phase 2: rank-16 update of non-panel columns
        const int pq0 = K0 >> 2;
        const bool act = (qq < pq0) || (qq >= pq0 + 4);
        float4 Rq[16];
        if (act) {
            #pragma unroll
            for (int m = 0; m < 16; ++m) Rq[m] = *(float4*)&rB[m][qq << 2];
        }
        #pragma unroll 2
        for (int r = 0; r < 16; ++r) {
            const int i = rh * 16 + r;
            float4 c0 = *(float4*)&sM[i][K0];
            float4 c1 = *(float4*)&sM[i][K0 + 4];
            float4 c2 = *(float4*)&sM[i][K0 + 8];
            float4 c3 = *(float4*)&sM[i][K0 + 12];
            if (act) {
                const bool prow = (i >= K0) && (i < K0 + 16);
                float4 acc;
                if (prow) { acc.x = acc.y = acc.z = acc.w = 0.f; }
                else        acc = *(float4*)&sM[i][qq << 2];
                FMA4(acc, c0.x, Rq[0]);  FMA4(acc, c0.y, Rq[1]);
                FMA4(acc, c0.z, Rq[2]);  FMA4(acc, c0.w, Rq[3]);
                FMA4(acc, c1.x, Rq[4]);  FMA4(acc, c1.y, Rq[5]);
                FMA4(acc, c1.z, Rq[6]);  FMA4(acc, c1.w, Rq[7]);
                FMA4(acc, c2.x, Rq[8]);  FMA4(acc, c2.y, Rq[9]);
                FMA4(acc, c2.z, Rq[10]); FMA4(acc, c2.w, Rq[11]);
                FMA4(acc, c3.x, Rq[12]); FMA4(acc, c3.y, Rq[13]);
                FMA4(acc, c3.z, Rq[14]); FMA4(acc, c3.w, Rq[15]);
                *(float4*)&sM[i][qq << 2] = acc;
            }
        }
        __syncthreads();
    }
    // write transposed: invMt[k][i] = invM[i][k]
    for (int flat = tid; flat < NN * NN; flat += 256) {
        const int kk = flat >> 7, ii = flat & 127;
        invMt[b * NN * NN + flat] = sM[ii][kk];
    }
}

// ---------------------------------------------------------------- K3: fused scan via 16x16x32 MFMA
// per block: (batch b, 16-col chunk dc). 4 waves x 2 row-tiles of 16 = 128 rows.
// XCD swizzle: bid&7 = XCD; the 4 dc-siblings of a batch share one XCD so their
// 64B half-line reads/writes merge in that XCD's L2.
// A-operands (LI, invM) fp16 hi + 2^-12*lo' in registers; y/u fp16 via LDS.
// kappa(h,e)=8h+e used for BOTH A and B k-maps (consistent bijection => correct).
__global__ __launch_bounds__(256, 1) void k_fused(const float* __restrict__ LIt,
                                                  const float* __restrict__ invMt,
                                                  const float* __restrict__ xs,
                                                  float* __restrict__ out) {
    __shared__ __align__(16) _Float16 yL[16][KSTR];
    __shared__ __align__(16) _Float16 uL[16][KSTR];

    const int bid = blockIdx.x;
    const int xcd = bid & 7, g = bid >> 3;
    const int dc = g & 3, b = (xcd << 2) | (g >> 2);
    const int tid = threadIdx.x;
    const int w = tid >> 6, l = tid & 63;
    const int cl = l & 15;       // column within chunk / A-row-within-tile / D-col
    const int h = l >> 4;        // k-subgroup (0..3) / D-row-group

    // zero y_0
    for (int q = tid; q < 16 * KSTR / 2; q += 256) ((unsigned*)yL)[q] = 0u;

    // ---- preload A-fragments (rows R of LI, invM), hi/lo split
    f16x8 LHi[2][4], LLo[2][4], VHi[2][4], VLo[2][4];
    {
        const float* Lb = LIt + b * NN * NN;
        const float* Vb = invMt + b * NN * NN;
        #pragma unroll
        for (int rt = 0; rt < 2; ++rt) {
            const int R = (2 * w + rt) * 16 + cl;
            #pragma unroll
            for (int ks = 0; ks < 4; ++ks) {
                #pragma unroll
                for (int e = 0; e < 8; ++e) {
                    const int k = ks * 32 + h * 8 + e;      // kappa(h,e)=8h+e
                    float fv = Lb[k * NN + R];
                    _Float16 fh = (_Float16)fv;
                    LHi[rt][ks][e] = fh;
                    LLo[rt][ks][e] = (_Float16)((fv - (float)fh) * 4096.0f);
                    float gv = Vb[k * NN + R];
                    _Float16 gh = (_Float16)gv;
                    VHi[rt][ks][e] = gh;
                    VLo[rt][ks][e] = (_Float16)((gv - (float)gh) * 4096.0f);
                }
            }
        }
    }

    const int tstr = NN * DD;
    const float* xbase = xs + (size_t)b * TT * tstr + dc * 16 + cl;
    float* obase = out + (size_t)b * TT * tstr + dc * 16 + cl;
    int roff[8];
    #pragma unroll
    for (int i = 0; i < 8; ++i)
        roff[i] = ((2 * w + (i >> 2)) * 16 + h * 4 + (i & 3)) * DD;  // D-layout rows

    float xcur[8], xnxt[8];
    #pragma unroll
    for (int i = 0; i < 8; ++i) xcur[i] = xbase[roff[i]];   // preload t=0

    LBAR();   // y_0 visible

    for (int t = 0; t < TT; ++t) {
        // prefetch x for t+1 — a full step (~600 cyc of MFMA/LDS) hides HBM latency
        if (t + 1 < TT) {
            #pragma unroll
            for (int i = 0; i < 8; ++i) xnxt[i] = xbase[(t + 1) * tstr + roff[i]];
        }

        // ---- phase A: u = LI*y + x   (4 independent chains of depth 4)
        f32x4v aH0 = {0.f,0.f,0.f,0.f}, aL0 = {0.f,0.f,0.f,0.f};
        f32x4v aH1 = {0.f,0.f,0.f,0.f}, aL1 = {0.f,0.f,0.f,0.f};
        #pragma unroll
        for (int ks = 0; ks < 4; ++ks) {
            f16x8 bf = *(const f16x8*)&yL[cl][ks * 32 + h * 8];
            aH0 = __builtin_amdgcn_mfma_f32_16x16x32_f16(LHi[0][ks], bf, aH0, 0, 0, 0);
            aL0 = __builtin_amdgcn_mfma_f32_16x16x32_f16(LLo[0][ks], bf, aL0, 0, 0, 0);
            aH1 = __builtin_amdgcn_mfma_f32_16x16x32_f16(LHi[1][ks], bf, aH1, 0, 0, 0);
            aL1 = __builtin_amdgcn_mfma_f32_16x16x32_f16(LLo[1][ks], bf, aL1, 0, 0, 0);
        }
        f16x4 u0, u1;
        #pragma unroll
        for (int j = 0; j < 4; ++j) {
            u0[j] = (_Float16)(__builtin_fmaf(aL0[j], 1.0f / 4096.0f, aH0[j]) + xcur[j]);
            u1[j] = (_Float16)(__builtin_fmaf(aL1[j], 1.0f / 4096.0f, aH1[j]) + xcur[4 + j]);
        }
        *(f16x4*)&uL[cl][(2 * w) * 16 + h * 4]     = u0;
        *(f16x4*)&uL[cl][(2 * w + 1) * 16 + h * 4] = u1;
        LBAR();

        // ---- phase B: y = invM*u
        f32x4v bH0 = {0.f,0.f,0.f,0.f}, bL0 = {0.f,0.f,0.f,0.f};
        f32x4v bH1 = {0.f,0.f,0.f,0.f}, bL1 = {0.f,0.f,0.f,0.f};
        #pragma unroll
        for (int ks = 0; ks < 4; ++ks) {
            f16x8 bf = *(const f16x8*)&uL[cl][ks * 32 + h * 8];
            bH0 = __builtin_amdgcn_mfma_f32_16x16x32_f16(VHi[0][ks], bf, bH0, 0, 0, 0);
            bL0 = __builtin_amdgcn_mfma_f32_16x16x32_f16(VLo[0][ks], bf, bL0, 0, 0, 0);
            bH1 = __builtin_amdgcn_mfma_f32_16x16x32_f16(VHi[1][ks], bf, bH1, 0, 0, 0);
            bL1 = __builtin_amdgcn_mfma_f32_16x16x32_f16(VLo[1][ks], bf, bL1, 0, 0, 0);
        }
        float y[8];
        #pragma unroll
        for (int j = 0; j < 4; ++j) {
            y[j]     = __builtin_fmaf(bL0[j], 1.0f / 4096.0f, bH0[j]);
            y[4 + j] = __builtin_fmaf(bL1[j], 1.0f / 4096.0f, bH1[j]);
        }
        // store y_t (fire-and-forget; barriers never drain vmcnt)
        #pragma unroll
        for (int i = 0; i < 8; ++i) obase[t * tstr + roff[i]] = y[i];
        // publish y_t as fp16 for next step
        f16x4 p0, p1;
        #pragma unroll
        for (int j = 0; j < 4; ++j) { p0[j] = (_Float16)y[j]; p1[j] = (_Float16)y[4 + j]; }
        *(f16x4*)&yL[cl][(2 * w) * 16 + h * 4]     = p0;
        *(f16x4*)&yL[cl][(2 * w + 1) * 16 + h * 4] = p1;
        LBAR();

        #pragma unroll
        for (int i = 0; i < 8; ++i) xcur[i] = xnxt[i];
    }
}

// ----------------------------------------------------------------
extern "C" void kernel_launch(void* const* d_in, const int* in_sizes, int n_in,
                              void* d_out, int out_size, void* d_ws, size_t ws_size,
                              hipStream_t stream) {
    const float* xs = (const float*)d_in[0];   // [32,256,128,64]
    const float* A  = (const float*)d_in[1];   // [32,128,128]
    float* out = (float*)d_out;                // [32,256,128,64]
    float* ws = (float*)d_ws;                  // needs 6 MB

    float* Mg    = ws;                          // [32][128][128]
    float* invMt = ws + 1 * BB * NN * NN;       // invM^T per batch
    float* LIt   = ws + 2 * BB * NN * NN;       // LI^T per batch

    k_build <<<BB, 256, 0, stream>>>(A, Mg, LIt);
    k_invert<<<BB, 256, 0, stream>>>(Mg, invMt);
    k_fused <<<BB * 4, 256, 0, stream>>>(LIt, invMt, xs, out);
}

// Round 6
// 336.654 us; speedup vs baseline: 3.3268x; 1.0284x over previous
//
#include <hip/hip_runtime.h>

#define BB 32
#define TT 256
#define NN 128
#define DD 64
#define KSTR 136   // LDS column stride in halves: 272B -> 16B-aligned b128 frags, worst 2-way (free) bank aliasing

typedef _Float16 f16x4 __attribute__((ext_vector_type(4)));
typedef _Float16 f16x8 __attribute__((ext_vector_type(8)));
typedef float    f32x4v __attribute__((ext_vector_type(4)));

#define FMA4(acc, s, v) do { \
    acc.x = __builtin_fmaf((s), (v).x, acc.x); \
    acc.y = __builtin_fmaf((s), (v).y, acc.y); \
    acc.z = __builtin_fmaf((s), (v).z, acc.z); \
    acc.w = __builtin_fmaf((s), (v).w, acc.w); } while (0)

// barrier that drains only LDS (lgkmcnt) — keeps global prefetch loads / stores in flight
#define LBAR() do { asm volatile("s_waitcnt lgkmcnt(0)" ::: "memory"); \
                    __builtin_amdgcn_s_barrier(); } while (0)

// ---------------------------------------------------------------- K1: build M and LI^T
__global__ __launch_bounds__(256) void k_build(const float* __restrict__ A,
                                               float* __restrict__ Mg,
                                               float* __restrict__ LIt) {
    __shared__ float degs[NN];
    const int b = blockIdx.x;
    const int tid = threadIdx.x;
    const float* Ab = A + b * NN * NN;
    if (tid < NN) {
        float s = 0.f;
        const float4* A4 = (const float4*)(Ab + tid * NN);
        #pragma unroll 4
        for (int j = 0; j < NN / 4; ++j) { float4 v = A4[j]; s += v.x + v.y + v.z + v.w; }
        degs[tid] = s;
    }
    __syncthreads();
    for (int flat = tid; flat < NN * NN; flat += 256) {
        int i = flat >> 7, j = flat & 127;
        float a = Ab[flat];
        float base = -a + ((i == j) ? degs[i] : 0.f);
        Mg[b * NN * NN + flat] = base + ((i == j) ? 1.1f : 0.f);
        LIt[b * NN * NN + j * NN + i] = base + ((i == j) ? 0.1f : 0.f);
    }
}

// ---------------------------------------------------------------- K2: blocked Gauss-Jordan inverse -> invM^T
__global__ __launch_bounds__(256) void k_invert(const float* __restrict__ Mg,
                                                float* __restrict__ invMt) {
    __shared__ __align__(16) float sM[NN][132];   // 66 KB, stride 132 dwords
    __shared__ __align__(16) float rB[16][NN];    // 8 KB staged row-block (old values)
    const int b = blockIdx.x;
    const int tid = threadIdx.x;
    for (int flat = tid; flat < NN * NN; flat += 256)
        sM[flat >> 7][flat & 127] = Mg[b * NN * NN + flat];
    __syncthreads();

    const int jl = tid & 15;     // panel column (phase 1)
    const int rg = tid >> 4;     // row group: rows rg*8..rg*8+8 (phase 1)
    const int qq = tid & 31;     // column quad (phase 2)
    const int rh = tid >> 5;     // row half-set: rows rh*16..rh*16+16 (phase 2)

    for (int pk = 0; pk < 8; ++pk) {
        const int K0 = pk << 4;
        // ---- phase 1: mini-GJ restricted to panel columns [K0, K0+16)
        for (int kl = 0; kl < 16; ++kl) {
            const int k = K0 + kl;
            const float pv  = sM[k][K0 + kl];
            const float akj = sM[k][K0 + jl];
            float f[8], v[8];
            #pragma unroll
            for (int r = 0; r < 8; ++r) {
                f[r] = sM[rg * 8 + r][K0 + kl];
                v[r] = sM[rg * 8 + r][K0 + jl];
            }
            __syncthreads();                  // all old values read before any write
            const float p = 1.0f / pv;
            const float pak = p * akj;
            #pragma unroll
            for (int r = 0; r < 8; ++r) {
                const int i = rg * 8 + r;
                float nv;
                if (i == k) nv = (jl == kl) ? p : akj * p;
                else        nv = (jl == kl) ? -f[r] * p : v[r] - f[r] * pak;
                sM[i][K0 + jl] = nv;
            }
            __syncthreads();
        }
        // ---- stage old row-block R = sM[K0..K0+16)[all cols]
        for (int q = tid; q < 16 * NN / 4; q += 256) {
            const int m = q >> 5, j4 = (q & 31) << 2;
            *(float4*)&rB[m][j4] = *(float4*)&sM[K0 + m][j4];
        }
        __syncthreads();
        // ---- phase 2: rank-16 update of non-panel columns
        const int pq0 = K0 >> 2;
        const bool act = (qq < pq0) || (qq >= pq0 + 4);
        float4 Rq[16];
        if (act) {
            #pragma unroll
            for (int m = 0; m < 16; ++m) Rq[m] = *(float4*)&rB[m][qq << 2];
        }
        #pragma unroll 2
        for (int r = 0; r < 16; ++r) {
            const int i = rh * 16 + r;
            float4 c0 = *(float4*)&sM[i][K0];
            float4 c1 = *(float4*)&sM[i][K0 + 4];
            float4 c2 = *(float4*)&sM[i][K0 + 8];
            float4 c3 = *(float4*)&sM[i][K0 + 12];
            if (act) {
                const bool prow = (i >= K0) && (i < K0 + 16);
                float4 acc;
                if (prow) { acc.x = acc.y = acc.z = acc.w = 0.f; }
                else        acc = *(float4*)&sM[i][qq << 2];
                FMA4(acc, c0.x, Rq[0]);  FMA4(acc, c0.y, Rq[1]);
                FMA4(acc, c0.z, Rq[2]);  FMA4(acc, c0.w, Rq[3]);
                FMA4(acc, c1.x, Rq[4]);  FMA4(acc, c1.y, Rq[5]);
                FMA4(acc, c1.z, Rq[6]);  FMA4(acc, c1.w, Rq[7]);
                FMA4(acc, c2.x, Rq[8]);  FMA4(acc, c2.y, Rq[9]);
                FMA4(acc, c2.z, Rq[10]); FMA4(acc, c2.w, Rq[11]);
                FMA4(acc, c3.x, Rq[12]); FMA4(acc, c3.y, Rq[13]);
                FMA4(acc, c3.z, Rq[14]); FMA4(acc, c3.w, Rq[15]);
                *(float4*)&sM[i][qq << 2] = acc;
            }
        }
        __syncthreads();
    }
    // write transposed: invMt[k][i] = invM[i][k]
    for (int flat = tid; flat < NN * NN; flat += 256) {
        const int kk = flat >> 7, ii = flat & 127;
        invMt[b * NN * NN + flat] = sM[ii][kk];
    }
}

// ---------------------------------------------------------------- K3: Wt[j][i] = sum_k invMt[k][i] * LIt[j][k]  (W = invM*LI, fp32)
__global__ __launch_bounds__(256) void k_wmat(const float* __restrict__ invMt,
                                              const float* __restrict__ LIt,
                                              float* __restrict__ Wt) {
    __shared__ float4 sLIt4s[16 * NN / 4];  // 8 KB: rows j = jg*16 .. +16
    float* sLIt = (float*)sLIt4s;
    const int bid = blockIdx.x;
    const int b = bid & 31, jg = bid >> 5;
    const int tid = threadIdx.x;
    const float4* LIt4 = (const float4*)(LIt + b * NN * NN + jg * 16 * NN);
    for (int q = tid; q < 512; q += 256) sLIt4s[q] = LIt4[q];
    __syncthreads();

    const int i4 = tid & 31;    // i0 = 4*i4
    const int jl0 = tid >> 5;   // 0..7 ; handles j-local jl0 and jl0+8
    const float4* inv4 = (const float4*)(invMt + b * NN * NN);
    float4 acc0 = {0, 0, 0, 0}, acc1 = {0, 0, 0, 0};
    #pragma unroll 4
    for (int k = 0; k < NN; ++k) {
        float4 m4 = inv4[k * 32 + i4];
        float l0 = sLIt[jl0 * NN + k];
        float l1 = sLIt[(jl0 + 8) * NN + k];
        FMA4(acc0, l0, m4);
        FMA4(acc1, l1, m4);
    }
    float4* Wt4 = (float4*)(Wt + b * NN * NN);
    int j0 = jg * 16 + jl0;
    Wt4[j0 * 32 + i4] = acc0;
    Wt4[(j0 + 8) * 32 + i4] = acc1;
}

// ---------------------------------------------------------------- K4: composed scan, 1 barrier/step
// y_t = W*y_{t-1} + q_t,  q_t = invM*x_t computed ONE STEP AHEAD (off critical path).
// Double-buffered yL and xL (fp16, column-major [col][row]); x loads issued 2 steps
// ahead of LDS staging; barriers drain lgkmcnt only. kappa(h,e)=8h+e on A and B.
__global__ __launch_bounds__(256, 1) void k_fused(const float* __restrict__ Wt,
                                                  const float* __restrict__ invMt,
                                                  const float* __restrict__ xs,
                                                  float* __restrict__ out) {
    __shared__ __align__(16) _Float16 yL[2][16][KSTR];
    __shared__ __align__(16) _Float16 xL[2][16][KSTR];

    const int bid = blockIdx.x;
    const int xcd = bid & 7, g = bid >> 3;
    const int dc = g & 3, b = (xcd << 2) | (g >> 2);   // 4 dc-siblings of a batch share an XCD
    const int tid = threadIdx.x;
    const int w = tid >> 6, l = tid & 63;
    const int cl = l & 15;       // column within chunk / A-row-within-tile / D-col
    const int h = l >> 4;        // k-subgroup (0..3) / D-row-group

    // zero y_{-1} (buffer 0)
    for (int q = tid; q < 16 * KSTR / 2; q += 256) ((unsigned*)yL[0])[q] = 0u;

    // ---- preload A-fragments (rows R of W, invM), hi/lo split
    f16x8 WHi[2][4], WLo[2][4], VHi[2][4], VLo[2][4];
    {
        const float* Wb = Wt + b * NN * NN;
        const float* Vb = invMt + b * NN * NN;
        #pragma unroll
        for (int rt = 0; rt < 2; ++rt) {
            const int R = (2 * w + rt) * 16 + cl;
            #pragma unroll
            for (int ks = 0; ks < 4; ++ks) {
                #pragma unroll
                for (int e = 0; e < 8; ++e) {
                    const int k = ks * 32 + h * 8 + e;      // kappa(h,e)=8h+e
                    float fv = Wb[k * NN + R];              // Wt[k][R] = W[R][k]
                    _Float16 fh = (_Float16)fv;
                    WHi[rt][ks][e] = fh;
                    WLo[rt][ks][e] = (_Float16)((fv - (float)fh) * 4096.0f);
                    float gv = Vb[k * NN + R];
                    _Float16 gh = (_Float16)gv;
                    VHi[rt][ks][e] = gh;
                    VLo[rt][ks][e] = (_Float16)((gv - (float)gh) * 4096.0f);
                }
            }
        }
    }

    const int tstr = NN * DD;
    const float* xbase = xs + (size_t)b * TT * tstr + dc * 16 + cl;
    float* obase = out + (size_t)b * TT * tstr + dc * 16 + cl;
    int roff[8];
    #pragma unroll
    for (int i = 0; i < 8; ++i)
        roff[i] = ((2 * w + (i >> 2)) * 16 + h * 4 + (i & 3)) * DD;  // D-layout rows
    const int yrow0 = (2 * w) * 16 + h * 4;
    const int yrow1 = (2 * w + 1) * 16 + h * 4;

    float q_cur[8];
    float xA[8], xB[8];

    // ---- prologue: stage x_0, compute q_0; stage x_1; issue x_2, x_3
    {
        float x0r[8], x1r[8];
        #pragma unroll
        for (int i = 0; i < 8; ++i) x0r[i] = xbase[roff[i]];
        #pragma unroll
        for (int i = 0; i < 8; ++i) x1r[i] = xbase[tstr + roff[i]];
        f16x4 p0, p1;
        #pragma unroll
        for (int j = 0; j < 4; ++j) { p0[j] = (_Float16)x0r[j]; p1[j] = (_Float16)x0r[4 + j]; }
        *(f16x4*)&xL[0][cl][yrow0] = p0;
        *(f16x4*)&xL[0][cl][yrow1] = p1;
        LBAR();   // xL[0] + zeroed yL[0] visible

        f32x4v qH0 = {0,0,0,0}, qL0 = {0,0,0,0}, qH1 = {0,0,0,0}, qL1 = {0,0,0,0};
        #pragma unroll
        for (int ks = 0; ks < 4; ++ks) {
            f16x8 bx = *(const f16x8*)&xL[0][cl][ks * 32 + h * 8];
            qH0 = __builtin_amdgcn_mfma_f32_16x16x32_f16(VHi[0][ks], bx, qH0, 0, 0, 0);
            qL0 = __builtin_amdgcn_mfma_f32_16x16x32_f16(VLo[0][ks], bx, qL0, 0, 0, 0);
            qH1 = __builtin_amdgcn_mfma_f32_16x16x32_f16(VHi[1][ks], bx, qH1, 0, 0, 0);
            qL1 = __builtin_amdgcn_mfma_f32_16x16x32_f16(VLo[1][ks], bx, qL1, 0, 0, 0);
        }
        #pragma unroll
        for (int j = 0; j < 4; ++j) {
            q_cur[j]     = __builtin_fmaf(qL0[j], 1.0f / 4096.0f, qH0[j]);
            q_cur[4 + j] = __builtin_fmaf(qL1[j], 1.0f / 4096.0f, qH1[j]);
        }
        #pragma unroll
        for (int j = 0; j < 4; ++j) { p0[j] = (_Float16)x1r[j]; p1[j] = (_Float16)x1r[4 + j]; }
        *(f16x4*)&xL[1][cl][yrow0] = p0;
        *(f16x4*)&xL[1][cl][yrow1] = p1;
        #pragma unroll
        for (int i = 0; i < 8; ++i) xA[i] = xbase[2 * tstr + roff[i]];
        #pragma unroll
        for (int i = 0; i < 8; ++i) xB[i] = xbase[3 * tstr + roff[i]];
        LBAR();   // xL[1] visible
    }

    // ---- main loop: entry invariants at step t:
    //   yL[t&1] = y_{t-1}; xL[(t+1)&1] = x_{t+1}; q_cur = q_t; xA = x_{t+2}; xB = x_{t+3} (in flight)
    #pragma unroll 2
    for (int t = 0; t < TT; ++t) {
        const int pr = t & 1, pw = pr ^ 1;
        float xC[8];
        const int tl = (t + 4 < TT) ? (t + 4) : (TT - 1);
        #pragma unroll
        for (int i = 0; i < 8; ++i) xC[i] = xbase[tl * tstr + roff[i]];

        // critical path: W * y_{t-1}
        f32x4v wH0 = {0,0,0,0}, wL0 = {0,0,0,0}, wH1 = {0,0,0,0}, wL1 = {0,0,0,0};
        #pragma unroll
        for (int ks = 0; ks < 4; ++ks) {
            f16x8 by = *(const f16x8*)&yL[pr][cl][ks * 32 + h * 8];
            wH0 = __builtin_amdgcn_mfma_f32_16x16x32_f16(WHi[0][ks], by, wH0, 0, 0, 0);
            wL0 = __builtin_amdgcn_mfma_f32_16x16x32_f16(WLo[0][ks], by, wL0, 0, 0, 0);
            wH1 = __builtin_amdgcn_mfma_f32_16x16x32_f16(WHi[1][ks], by, wH1, 0, 0, 0);
            wL1 = __builtin_amdgcn_mfma_f32_16x16x32_f16(WLo[1][ks], by, wL1, 0, 0, 0);
        }
        // shadow: q_{t+1} = invM * x_{t+1}
        f32x4v qH0 = {0,0,0,0}, qL0 = {0,0,0,0}, qH1 = {0,0,0,0}, qL1 = {0,0,0,0};
        #pragma unroll
        for (int ks = 0; ks < 4; ++ks) {
            f16x8 bx = *(const f16x8*)&xL[pw][cl][ks * 32 + h * 8];
            qH0 = __builtin_amdgcn_mfma_f32_16x16x32_f16(VHi[0][ks], bx, qH0, 0, 0, 0);
            qL0 = __builtin_amdgcn_mfma_f32_16x16x32_f16(VLo[0][ks], bx, qL0, 0, 0, 0);
            qH1 = __builtin_amdgcn_mfma_f32_16x16x32_f16(VHi[1][ks], bx, qH1, 0, 0, 0);
            qL1 = __builtin_amdgcn_mfma_f32_16x16x32_f16(VLo[1][ks], bx, qL1, 0, 0, 0);
        }

        float y[8];
        #pragma unroll
        for (int j = 0; j < 4; ++j) {
            y[j]     = __builtin_fmaf(wL0[j], 1.0f / 4096.0f, wH0[j]) + q_cur[j];
            y[4 + j] = __builtin_fmaf(wL1[j], 1.0f / 4096.0f, wH1[j]) + q_cur[4 + j];
        }
        // store y_t (fire-and-forget; barriers never drain vmcnt)
        #pragma unroll
        for (int i = 0; i < 8; ++i) obase[t * tstr + roff[i]] = y[i];
        // publish y_t (fp16) into the write buffer
        f16x4 p0, p1;
        #pragma unroll
        for (int j = 0; j < 4; ++j) { p0[j] = (_Float16)y[j]; p1[j] = (_Float16)y[4 + j]; }
        *(f16x4*)&yL[pw][cl][yrow0] = p0;
        *(f16x4*)&yL[pw][cl][yrow1] = p1;
        // stage x_{t+2} into xL[t&1] (its old content x_t was consumed at step t-1)
        #pragma unroll
        for (int j = 0; j < 4; ++j) { p0[j] = (_Float16)xA[j]; p1[j] = (_Float16)xA[4 + j]; }
        *(f16x4*)&xL[pr][cl][yrow0] = p0;
        *(f16x4*)&xL[pr][cl][yrow1] = p1;
        // q for next step
        #pragma unroll
        for (int j = 0; j < 4; ++j) {
            q_cur[j]     = __builtin_fmaf(qL0[j], 1.0f / 4096.0f, qH0[j]);
            q_cur[4 + j] = __builtin_fmaf(qL1[j], 1.0f / 4096.0f, qH1[j]);
        }
        #pragma unroll
        for (int i = 0; i < 8; ++i) { xA[i] = xB[i]; xB[i] = xC[i]; }
        LBAR();
    }
}

// ----------------------------------------------------------------
extern "C" void kernel_launch(void* const* d_in, const int* in_sizes, int n_in,
                              void* d_out, int out_size, void* d_ws, size_t ws_size,
                              hipStream_t stream) {
    const float* xs = (const float*)d_in[0];   // [32,256,128,64]
    const float* A  = (const float*)d_in[1];   // [32,128,128]
    float* out = (float*)d_out;                // [32,256,128,64]
    float* ws = (float*)d_ws;                  // needs 8 MB

    float* Mg    = ws;                          // [32][128][128]
    float* invMt = ws + 1 * BB * NN * NN;       // invM^T per batch
    float* LIt   = ws + 2 * BB * NN * NN;       // LI^T per batch
    float* Wtm   = ws + 3 * BB * NN * NN;       // W^T per batch

    k_build <<<BB, 256, 0, stream>>>(A, Mg, LIt);
    k_invert<<<BB, 256, 0, stream>>>(Mg, invMt);
    k_wmat  <<<256, 256, 0, stream>>>(invMt, LIt, Wtm);
    k_fused <<<BB * 4, 256, 0, stream>>>(Wtm, invMt, xs, out);
}

// Round 7
// 329.770 us; speedup vs baseline: 3.3962x; 1.0209x over previous
//
#include <hip/hip_runtime.h>

#define BB 32
#define TT 256
#define NN 128
#define DD 64
#define KSTR 136   // LDS column stride in halves: 272B -> 16B-aligned b128 frags, balanced bank-quad spread

typedef _Float16 f16x4 __attribute__((ext_vector_type(4)));
typedef _Float16 f16x8 __attribute__((ext_vector_type(8)));
typedef float    f32x4v __attribute__((ext_vector_type(4)));

#define FMA4(acc, s, v) do { \
    acc.x = __builtin_fmaf((s), (v).x, acc.x); \
    acc.y = __builtin_fmaf((s), (v).y, acc.y); \
    acc.z = __builtin_fmaf((s), (v).z, acc.z); \
    acc.w = __builtin_fmaf((s), (v).w, acc.w); } while (0)

// barrier that drains only LDS (lgkmcnt) — keeps global prefetch loads / stores in flight
#define LBAR() do { asm volatile("s_waitcnt lgkmcnt(0)" ::: "memory"); \
                    __builtin_amdgcn_s_barrier(); } while (0)

// ---------------------------------------------------------------- K1: build M and LI^T
__global__ __launch_bounds__(256) void k_build(const float* __restrict__ A,
                                               float* __restrict__ Mg,
                                               float* __restrict__ LIt) {
    __shared__ float degs[NN];
    const int b = blockIdx.x;
    const int tid = threadIdx.x;
    const float* Ab = A + b * NN * NN;
    if (tid < NN) {
        float s = 0.f;
        const float4* A4 = (const float4*)(Ab + tid * NN);
        #pragma unroll 4
        for (int j = 0; j < NN / 4; ++j) { float4 v = A4[j]; s += v.x + v.y + v.z + v.w; }
        degs[tid] = s;
    }
    __syncthreads();
    for (int flat = tid; flat < NN * NN; flat += 256) {
        int i = flat >> 7, j = flat & 127;
        float a = Ab[flat];
        float base = -a + ((i == j) ? degs[i] : 0.f);
        Mg[b * NN * NN + flat] = base + ((i == j) ? 1.1f : 0.f);
        LIt[b * NN * NN + j * NN + i] = base + ((i == j) ? 0.1f : 0.f);
    }
}

// ---------------------------------------------------------------- K2: blocked Gauss-Jordan inverse -> invM^T
__global__ __launch_bounds__(256) void k_invert(const float* __restrict__ Mg,
                                                float* __restrict__ invMt) {
    __shared__ __align__(16) float sM[NN][132];   // 66 KB, stride 132 dwords
    __shared__ __align__(16) float rB[16][NN];    // 8 KB staged row-block (old values)
    const int b = blockIdx.x;
    const int tid = threadIdx.x;
    for (int flat = tid; flat < NN * NN; flat += 256)
        sM[flat >> 7][flat & 127] = Mg[b * NN * NN + flat];
    __syncthreads();

    const int jl = tid & 15;     // panel column (phase 1)
    const int rg = tid >> 4;     // row group: rows rg*8..rg*8+8 (phase 1)
    const int qq = tid & 31;     // column quad (phase 2)
    const int rh = tid >> 5;     // row half-set: rows rh*16..rh*16+16 (phase 2)

    for (int pk = 0; pk < 8; ++pk) {
        const int K0 = pk << 4;
        // ---- phase 1: mini-GJ restricted to panel columns [K0, K0+16)
        for (int kl = 0; kl < 16; ++kl) {
            const int k = K0 + kl;
            const float pv  = sM[k][K0 + kl];
            const float akj = sM[k][K0 + jl];
            float f[8], v[8];
            #pragma unroll
            for (int r = 0; r < 8; ++r) {
                f[r] = sM[rg * 8 + r][K0 + kl];
                v[r] = sM[rg * 8 + r][K0 + jl];
            }
            __syncthreads();                  // all old values read before any write
            const float p = 1.0f / pv;
            const float pak = p * akj;
            #pragma unroll
            for (int r = 0; r < 8; ++r) {
                const int i = rg * 8 + r;
                float nv;
                if (i == k) nv = (jl == kl) ? p : akj * p;
                else        nv = (jl == kl) ? -f[r] * p : v[r] - f[r] * pak;
                sM[i][K0 + jl] = nv;
            }
            __syncthreads();
        }
        // ---- stage old row-block R = sM[K0..K0+16)[all cols]
        for (int q = tid; q < 16 * NN / 4; q += 256) {
            const int m = q >> 5, j4 = (q & 31) << 2;
            *(float4*)&rB[m][j4] = *(float4*)&sM[K0 + m][j4];
        }
        __syncthreads();
        // ---- phase 2: rank-16 update of non-panel columns
        const int pq0 = K0 >> 2;
        const bool act = (qq < pq0) || (qq >= pq0 + 4);
        float4 Rq[16];
        if (act) {
            #pragma unroll
            for (int m = 0; m < 16; ++m) Rq[m] = *(float4*)&rB[m][qq << 2];
        }
        #pragma unroll 2
        for (int r = 0; r < 16; ++r) {
            const int i = rh * 16 + r;
            float4 c0 = *(float4*)&sM[i][K0];
            float4 c1 = *(float4*)&sM[i][K0 + 4];
            float4 c2 = *(float4*)&sM[i][K0 + 8];
            float4 c3 = *(float4*)&sM[i][K0 + 12];
            if (act) {
                const bool prow = (i >= K0) && (i < K0 + 16);
                float4 acc;
                if (prow) { acc.x = acc.y = acc.z = acc.w = 0.f; }
                else        acc = *(float4*)&sM[i][qq << 2];
                FMA4(acc, c0.x, Rq[0]);  FMA4(acc, c0.y, Rq[1]);
                FMA4(acc, c0.z, Rq[2]);  FMA4(acc, c0.w, Rq[3]);
                FMA4(acc, c1.x, Rq[4]);  FMA4(acc, c1.y, Rq[5]);
                FMA4(acc, c1.z, Rq[6]);  FMA4(acc, c1.w, Rq[7]);
                FMA4(acc, c2.x, Rq[8]);  FMA4(acc, c2.y, Rq[9]);
                FMA4(acc, c2.z, Rq[10]); FMA4(acc, c2.w, Rq[11]);
                FMA4(acc, c3.x, Rq[12]); FMA4(acc, c3.y, Rq[13]);
                FMA4(acc, c3.z, Rq[14]); FMA4(acc, c3.w, Rq[15]);
                *(float4*)&sM[i][qq << 2] = acc;
            }
        }
        __syncthreads();
    }
    // write transposed: invMt[k][i] = invM[i][k]
    for (int flat = tid; flat < NN * NN; flat += 256) {
        const int kk = flat >> 7, ii = flat & 127;
        invMt[b * NN * NN + flat] = sM[ii][kk];
    }
}

// ---------------------------------------------------------------- K3: Wt[j][i] = sum_k invMt[k][i] * LIt[j][k]  (W = invM*LI, fp32)
__global__ __launch_bounds__(256) void k_wmat(const float* __restrict__ invMt,
                                              const float* __restrict__ LIt,
                                              float* __restrict__ Wt) {
    __shared__ float4 sLIt4s[16 * NN / 4];  // 8 KB: rows j = jg*16 .. +16
    float* sLIt = (float*)sLIt4s;
    const int bid = blockIdx.x;
    const int b = bid & 31, jg = bid >> 5;
    const int tid = threadIdx.x;
    const float4* LIt4 = (const float4*)(LIt + b * NN * NN + jg * 16 * NN);
    for (int q = tid; q < 512; q += 256) sLIt4s[q] = LIt4[q];
    __syncthreads();

    const int i4 = tid & 31;    // i0 = 4*i4
    const int jl0 = tid >> 5;   // 0..7 ; handles j-local jl0 and jl0+8
    const float4* inv4 = (const float4*)(invMt + b * NN * NN);
    float4 acc0 = {0, 0, 0, 0}, acc1 = {0, 0, 0, 0};
    #pragma unroll 4
    for (int k = 0; k < NN; ++k) {
        float4 m4 = inv4[k * 32 + i4];
        float l0 = sLIt[jl0 * NN + k];
        float l1 = sLIt[(jl0 + 8) * NN + k];
        FMA4(acc0, l0, m4);
        FMA4(acc1, l1, m4);
    }
    float4* Wt4 = (float4*)(Wt + b * NN * NN);
    int j0 = jg * 16 + jl0;
    Wt4[j0 * 32 + i4] = acc0;
    Wt4[(j0 + 8) * 32 + i4] = acc1;
}

// ---------------------------------------------------------------- K4: composed scan, 8 waves (2/SIMD), 1 barrier/step
// y_t = W*y_{t-1} + q_t,  q_t = invM*x_t computed ONE STEP AHEAD (off critical path).
// 512 threads: wave w owns row-tile [16w,16w+16) x 16 cols. 2 waves/SIMD interleave
// each other's MFMA-chain / LDS / HBM latencies (the round-6 idle was 1 wave/SIMD).
// Double-buffered yL/xL fp16; x loads 4 steps ahead; barriers drain lgkmcnt only.
__global__ __launch_bounds__(512, 1) void k_fused(const float* __restrict__ Wt,
                                                  const float* __restrict__ invMt,
                                                  const float* __restrict__ xs,
                                                  float* __restrict__ out) {
    __shared__ __align__(16) _Float16 yL[2][16][KSTR];
    __shared__ __align__(16) _Float16 xL[2][16][KSTR];

    const int bid = blockIdx.x;
    const int xcd = bid & 7, g = bid >> 3;
    const int dc = g & 3, b = (xcd << 2) | (g >> 2);   // 4 dc-siblings of a batch share an XCD
    const int tid = threadIdx.x;
    const int w = tid >> 6, l = tid & 63;
    const int cl = l & 15;       // column within chunk / A-row-within-tile / D-col
    const int h = l >> 4;        // k-subgroup (0..3) / D-row-group

    // zero y_{-1} (buffer 0): 16*KSTR/2 = 1088 dwords
    for (int q = tid; q < 16 * KSTR / 2; q += 512) ((unsigned*)yL[0])[q] = 0u;

    // ---- preload A-fragments (rows R = 16w+cl of W, invM), hi/lo split
    f16x8 WHi[4], WLo[4], VHi[4], VLo[4];
    {
        const float* Wb = Wt + b * NN * NN;
        const float* Vb = invMt + b * NN * NN;
        const int R = w * 16 + cl;
        #pragma unroll
        for (int ks = 0; ks < 4; ++ks) {
            #pragma unroll
            for (int e = 0; e < 8; ++e) {
                const int k = ks * 32 + h * 8 + e;      // kappa(h,e)=8h+e
                float fv = Wb[k * NN + R];              // Wt[k][R] = W[R][k]
                _Float16 fh = (_Float16)fv;
                WHi[ks][e] = fh;
                WLo[ks][e] = (_Float16)((fv - (float)fh) * 4096.0f);
                float gv = Vb[k * NN + R];
                _Float16 gh = (_Float16)gv;
                VHi[ks][e] = gh;
                VLo[ks][e] = (_Float16)((gv - (float)gh) * 4096.0f);
            }
        }
    }

    const int tstr = NN * DD;
    const float* xbase = xs + (size_t)b * TT * tstr + dc * 16 + cl;
    float* obase = out + (size_t)b * TT * tstr + dc * 16 + cl;
    int roff[4];
    #pragma unroll
    for (int j = 0; j < 4; ++j)
        roff[j] = (w * 16 + h * 4 + j) * DD;   // D-layout rows of this lane
    const int yrow = w * 16 + h * 4;

    float q_cur[4];
    float xA[4], xB[4];

    // ---- prologue: stage x_0, compute q_0; stage x_1; issue x_2, x_3
    {
        float x0r[4], x1r[4];
        #pragma unroll
        for (int j = 0; j < 4; ++j) x0r[j] = xbase[roff[j]];
        #pragma unroll
        for (int j = 0; j < 4; ++j) x1r[j] = xbase[tstr + roff[j]];
        f16x4 p0;
        #pragma unroll
        for (int j = 0; j < 4; ++j) p0[j] = (_Float16)x0r[j];
        *(f16x4*)&xL[0][cl][yrow] = p0;
        LBAR();   // xL[0] + zeroed yL[0] visible

        f32x4v qH = {0,0,0,0}, qL = {0,0,0,0};
        #pragma unroll
        for (int ks = 0; ks < 4; ++ks) {
            f16x8 bx = *(const f16x8*)&xL[0][cl][ks * 32 + h * 8];
            qH = __builtin_amdgcn_mfma_f32_16x16x32_f16(VHi[ks], bx, qH, 0, 0, 0);
            qL = __builtin_amdgcn_mfma_f32_16x16x32_f16(VLo[ks], bx, qL, 0, 0, 0);
        }
        #pragma unroll
        for (int j = 0; j < 4; ++j)
            q_cur[j] = __builtin_fmaf(qL[j], 1.0f / 4096.0f, qH[j]);
        #pragma unroll
        for (int j = 0; j < 4; ++j) p0[j] = (_Float16)x1r[j];
        *(f16x4*)&xL[1][cl][yrow] = p0;
        #pragma unroll
        for (int j = 0; j < 4; ++j) xA[j] = xbase[2 * tstr + roff[j]];
        #pragma unroll
        for (int j = 0; j < 4; ++j) xB[j] = xbase[3 * tstr + roff[j]];
        LBAR();   // xL[1] visible
    }

    // ---- main loop: entry invariants at step t:
    //   yL[t&1] = y_{t-1}; xL[(t+1)&1] = x_{t+1}; q_cur = q_t; xA = x_{t+2}; xB = x_{t+3} (in flight)
    #pragma unroll 2
    for (int t = 0; t < TT; ++t) {
        const int pr = t & 1, pw = pr ^ 1;
        float xC[4];
        const int tl = (t + 4 < TT) ? (t + 4) : (TT - 1);
        #pragma unroll
        for (int j = 0; j < 4; ++j) xC[j] = xbase[tl * tstr + roff[j]];

        // critical path: W * y_{t-1}
        f32x4v wH = {0,0,0,0}, wL = {0,0,0,0};
        #pragma unroll
        for (int ks = 0; ks < 4; ++ks) {
            f16x8 by = *(const f16x8*)&yL[pr][cl][ks * 32 + h * 8];
            wH = __builtin_amdgcn_mfma_f32_16x16x32_f16(WHi[ks], by, wH, 0, 0, 0);
            wL = __builtin_amdgcn_mfma_f32_16x16x32_f16(WLo[ks], by, wL, 0, 0, 0);
        }
        // shadow: q_{t+1} = invM * x_{t+1}
        f32x4v qH = {0,0,0,0}, qL = {0,0,0,0};
        #pragma unroll
        for (int ks = 0; ks < 4; ++ks) {
            f16x8 bx = *(const f16x8*)&xL[pw][cl][ks * 32 + h * 8];
            qH = __builtin_amdgcn_mfma_f32_16x16x32_f16(VHi[ks], bx, qH, 0, 0, 0);
            qL = __builtin_amdgcn_mfma_f32_16x16x32_f16(VLo[ks], bx, qL, 0, 0, 0);
        }

        float y[4];
        #pragma unroll
        for (int j = 0; j < 4; ++j)
            y[j] = __builtin_fmaf(wL[j], 1.0f / 4096.0f, wH[j]) + q_cur[j];
        // store y_t (fire-and-forget; barriers never drain vmcnt)
        #pragma unroll
        for (int j = 0; j < 4; ++j) obase[t * tstr + roff[j]] = y[j];
        // publish y_t (fp16) into the write buffer
        f16x4 p0;
        #pragma unroll
        for (int j = 0; j < 4; ++j) p0[j] = (_Float16)y[j];
        *(f16x4*)&yL[pw][cl][yrow] = p0;
        // stage x_{t+2} into xL[t&1] (its old content x_t was consumed at step t-1)
        #pragma unroll
        for (int j = 0; j < 4; ++j) p0[j] = (_Float16)xA[j];
        *(f16x4*)&xL[pr][cl][yrow] = p0;
        // q for next step
        #pragma unroll
        for (int j = 0; j < 4; ++j)
            q_cur[j] = __builtin_fmaf(qL[j], 1.0f / 4096.0f, qH[j]);
        #pragma unroll
        for (int j = 0; j < 4; ++j) { xA[j] = xB[j]; xB[j] = xC[j]; }
        LBAR();
    }
}

// ----------------------------------------------------------------
extern "C" void kernel_launch(void* const* d_in, const int* in_sizes, int n_in,
                              void* d_out, int out_size, void* d_ws, size_t ws_size,
                              hipStream_t stream) {
    const float* xs = (const float*)d_in[0];   // [32,256,128,64]
    const float* A  = (const float*)d_in[1];   // [32,128,128]
    float* out = (float*)d_out;                // [32,256,128,64]
    float* ws = (float*)d_ws;                  // needs 8 MB

    float* Mg    = ws;                          // [32][128][128]
    float* invMt = ws + 1 * BB * NN * NN;       // invM^T per batch
    float* LIt   = ws + 2 * BB * NN * NN;       // LI^T per batch
    float* Wtm   = ws + 3 * BB * NN * NN;       // W^T per batch

    k_build <<<BB, 256, 0, stream>>>(A, Mg, LIt);
    k_invert<<<BB, 256, 0, stream>>>(Mg, invMt);
    k_wmat  <<<256, 256, 0, stream>>>(invMt, LIt, Wtm);
    k_fused <<<BB * 4, 512, 0, stream>>>(Wtm, invMt, xs, out);
}

// Round 8
// 287.599 us; speedup vs baseline: 3.8942x; 1.1466x over previous
//
#include <hip/hip_runtime.h>

#define BB 32
#define TT 256
#define NN 128
#define DD 64
#define KSTR 136   // dL column stride in halves: 272B -> 16B-aligned b128 frags

typedef _Float16 f16x4 __attribute__((ext_vector_type(4)));
typedef _Float16 f16x8 __attribute__((ext_vector_type(8)));
typedef float    f32x4v __attribute__((ext_vector_type(4)));

#define FMA4(acc, s, v) do { \
    acc.x = __builtin_fmaf((s), (v).x, acc.x); \
    acc.y = __builtin_fmaf((s), (v).y, acc.y); \
    acc.z = __builtin_fmaf((s), (v).z, acc.z); \
    acc.w = __builtin_fmaf((s), (v).w, acc.w); } while (0)

// barrier that drains only LDS (lgkmcnt) — keeps global prefetch loads / stores in flight
#define LBAR() do { asm volatile("s_waitcnt lgkmcnt(0)" ::: "memory"); \
                    __builtin_amdgcn_s_barrier(); } while (0)

// ---------------------------------------------------------------- K1: fused build + blocked Gauss-Jordan inverse -> invM^T
// M = L + 1.1*I built directly in LDS from A (deg row-sums in rB[0], consumed
// before rB is reused as GJ staging). Then panel-16 blocked GJ (validated r5-r7).
__global__ __launch_bounds__(256) void k_prep(const float* __restrict__ A,
                                              float* __restrict__ invMt) {
    __shared__ __align__(16) float sM[NN][132];   // 66 KB, stride 132 dwords
    __shared__ __align__(16) float rB[16][NN];    // 8 KB staging; rB[0] hosts deg first
    const int b = blockIdx.x;
    const int tid = threadIdx.x;
    const float* Ab = A + b * NN * NN;

    if (tid < NN) {
        float s = 0.f;
        const float4* A4 = (const float4*)(Ab + tid * NN);
        #pragma unroll 4
        for (int j = 0; j < NN / 4; ++j) { float4 v = A4[j]; s += v.x + v.y + v.z + v.w; }
        rB[0][tid] = s;
    }
    __syncthreads();
    for (int flat = tid; flat < NN * NN; flat += 256) {
        const int i = flat >> 7, j = flat & 127;
        const float a = Ab[flat];
        sM[i][j] = -a + ((i == j) ? (rB[0][i] + 1.1f) : 0.f);
    }
    __syncthreads();

    const int jl = tid & 15;     // panel column (phase 1)
    const int rg = tid >> 4;     // row group: rows rg*8..rg*8+8 (phase 1)
    const int qq = tid & 31;     // column quad (phase 2)
    const int rh = tid >> 5;     // row half-set: rows rh*16..rh*16+16 (phase 2)

    for (int pk = 0; pk < 8; ++pk) {
        const int K0 = pk << 4;
        // ---- phase 1: mini-GJ restricted to panel columns [K0, K0+16)
        for (int kl = 0; kl < 16; ++kl) {
            const int k = K0 + kl;
            const float pv  = sM[k][K0 + kl];
            const float akj = sM[k][K0 + jl];
            float f[8], v[8];
            #pragma unroll
            for (int r = 0; r < 8; ++r) {
                f[r] = sM[rg * 8 + r][K0 + kl];
                v[r] = sM[rg * 8 + r][K0 + jl];
            }
            __syncthreads();                  // all old values read before any write
            const float p = 1.0f / pv;
            const float pak = p * akj;
            #pragma unroll
            for (int r = 0; r < 8; ++r) {
                const int i = rg * 8 + r;
                float nv;
                if (i == k) nv = (jl == kl) ? p : akj * p;
                else        nv = (jl == kl) ? -f[r] * p : v[r] - f[r] * pak;
                sM[i][K0 + jl] = nv;
            }
            __syncthreads();
        }
        // ---- stage old row-block R = sM[K0..K0+16)[all cols]
        for (int q = tid; q < 16 * NN / 4; q += 256) {
            const int m = q >> 5, j4 = (q & 31) << 2;
            *(float4*)&rB[m][j4] = *(float4*)&sM[K0 + m][j4];
        }
        __syncthreads();
        // ---- phase 2: rank-16 update of non-panel columns
        const int pq0 = K0 >> 2;
        const bool act = (qq < pq0) || (qq >= pq0 + 4);
        float4 Rq[16];
        if (act) {
            #pragma unroll
            for (int m = 0; m < 16; ++m) Rq[m] = *(float4*)&rB[m][qq << 2];
        }
        #pragma unroll 2
        for (int r = 0; r < 16; ++r) {
            const int i = rh * 16 + r;
            float4 c0 = *(float4*)&sM[i][K0];
            float4 c1 = *(float4*)&sM[i][K0 + 4];
            float4 c2 = *(float4*)&sM[i][K0 + 8];
            float4 c3 = *(float4*)&sM[i][K0 + 12];
            if (act) {
                const bool prow = (i >= K0) && (i < K0 + 16);
                float4 acc;
                if (prow) { acc.x = acc.y = acc.z = acc.w = 0.f; }
                else        acc = *(float4*)&sM[i][qq << 2];
                FMA4(acc, c0.x, Rq[0]);  FMA4(acc, c0.y, Rq[1]);
                FMA4(acc, c0.z, Rq[2]);  FMA4(acc, c0.w, Rq[3]);
                FMA4(acc, c1.x, Rq[4]);  FMA4(acc, c1.y, Rq[5]);
                FMA4(acc, c1.z, Rq[6]);  FMA4(acc, c1.w, Rq[7]);
                FMA4(acc, c2.x, Rq[8]);  FMA4(acc, c2.y, Rq[9]);
                FMA4(acc, c2.z, Rq[10]); FMA4(acc, c2.w, Rq[11]);
                FMA4(acc, c3.x, Rq[12]); FMA4(acc, c3.y, Rq[13]);
                FMA4(acc, c3.z, Rq[14]); FMA4(acc, c3.w, Rq[15]);
                *(float4*)&sM[i][qq << 2] = acc;
            }
        }
        __syncthreads();
    }
    // write transposed: invMt[k][i] = invM[i][k]
    for (int flat = tid; flat < NN * NN; flat += 256) {
        const int kk = flat >> 7, ii = flat & 127;
        invMt[b * NN * NN + flat] = sM[ii][kk];
    }
}

// ---------------------------------------------------------------- K2: collapsed scan
// W = I - invM exactly (M - LI = I), so  y_t = y_{t-1} + invM*(x_t - y_{t-1}).
// ONE matvec/step; y lives in fp32 registers for all 256 steps; only d = x - y
// is fp16-quantized (published to double-buffered dL; one barrier/step).
// 8 waves (2/SIMD): wave w owns rows [16w,16w+16) of the (b, dc) 16-col unit.
// x prefetch: 4 slots, compile-time indices under x4 unroll -> loads issued at
// step t are consumed at t+4 (no per-step vmcnt tail). Barriers drain lgkm only.
__global__ __launch_bounds__(512, 1) void k_scan(const float* __restrict__ invMt,
                                                 const float* __restrict__ xs,
                                                 float* __restrict__ out) {
    __shared__ __align__(16) _Float16 dL[2][16][KSTR];

    const int bid = blockIdx.x;
    const int xcd = bid & 7, g = bid >> 3;
    const int dc = g & 3, b = (xcd << 2) | (g >> 2);   // 4 dc-siblings of a batch share an XCD
    const int tid = threadIdx.x;
    const int w = tid >> 6, l = tid & 63;
    const int cl = l & 15;       // column within chunk / A-row-within-tile / D-col
    const int h = l >> 4;        // k-subgroup (0..3) / D-row-group

    // ---- preload invM A-frags (rows R = 16w+cl), hi/lo split; kappa(h,e)=8h+e
    f16x8 VHi[4], VLo[4];
    {
        const float* Vb = invMt + b * NN * NN;
        const int R = w * 16 + cl;
        #pragma unroll
        for (int ks = 0; ks < 4; ++ks) {
            #pragma unroll
            for (int e = 0; e < 8; ++e) {
                const int k = ks * 32 + h * 8 + e;
                float gv = Vb[k * NN + R];              // invMt[k][R] = invM[R][k]
                _Float16 gh = (_Float16)gv;
                VHi[ks][e] = gh;
                VLo[ks][e] = (_Float16)((gv - (float)gh) * 4096.0f);
            }
        }
    }

    const int tstr = NN * DD;
    const float* xbase = xs + (size_t)b * TT * tstr + dc * 16 + cl;
    float* obase = out + (size_t)b * TT * tstr + dc * 16 + cl;
    int roff[4];
    #pragma unroll
    for (int j = 0; j < 4; ++j)
        roff[j] = (w * 16 + h * 4 + j) * DD;   // D-layout rows of this lane
    const int yrow = w * 16 + h * 4;

    float y[4] = {0.f, 0.f, 0.f, 0.f};
    float xsl[4][4];   // slot s holds x_{t'} with t' ≡ s (mod 4); static indexing only

    // ---- prologue: d_0 = x_0 (y_{-1}=0); fill slots with x_1..x_4
    {
        float x0r[4];
        #pragma unroll
        for (int j = 0; j < 4; ++j) x0r[j] = xbase[roff[j]];
        #pragma unroll
        for (int j = 0; j < 4; ++j) xsl[1][j] = xbase[1 * tstr + roff[j]];
        #pragma unroll
        for (int j = 0; j < 4; ++j) xsl[2][j] = xbase[2 * tstr + roff[j]];
        #pragma unroll
        for (int j = 0; j < 4; ++j) xsl[3][j] = xbase[3 * tstr + roff[j]];
        #pragma unroll
        for (int j = 0; j < 4; ++j) xsl[0][j] = xbase[4 * tstr + roff[j]];
        f16x4 p;
        #pragma unroll
        for (int j = 0; j < 4; ++j) p[j] = (_Float16)x0r[j];
        *(f16x4*)&dL[0][cl][yrow] = p;
        LBAR();   // d_0 visible
    }

    // ---- main loop: step t reads dL[t&1], publishes d_{t+1} into dL[(t+1)&1]
    for (int i = 0; i < TT / 4; ++i) {
        #pragma unroll
        for (int u = 0; u < 4; ++u) {
            const int t = 4 * i + u;
            const int pr = u & 1, pw = pr ^ 1;   // t&1 == u&1 (4i even)
            const int sl = (u + 1) & 3;          // slot holding x_{t+1}

            // m = invM * d_t  (hi/lo chains, depth 4, independent)
            f32x4v mH = {0.f,0.f,0.f,0.f}, mL = {0.f,0.f,0.f,0.f};
            #pragma unroll
            for (int ks = 0; ks < 4; ++ks) {
                f16x8 bf = *(const f16x8*)&dL[pr][cl][ks * 32 + h * 8];
                mH = __builtin_amdgcn_mfma_f32_16x16x32_f16(VHi[ks], bf, mH, 0, 0, 0);
                mL = __builtin_amdgcn_mfma_f32_16x16x32_f16(VLo[ks], bf, mL, 0, 0, 0);
            }
            #pragma unroll
            for (int j = 0; j < 4; ++j)
                y[j] += __builtin_fmaf(mL[j], 1.0f / 4096.0f, mH[j]);

            // store y_t (fire-and-forget; barriers never drain vmcnt)
            #pragma unroll
            for (int j = 0; j < 4; ++j) obase[t * tstr + roff[j]] = y[j];

            if (u != 3 || i != TT / 4 - 1) {     // all but the very last step
                // publish d_{t+1} = x_{t+1} - y_t
                f16x4 p;
                #pragma unroll
                for (int j = 0; j < 4; ++j) p[j] = (_Float16)(xsl[sl][j] - y[j]);
                *(f16x4*)&dL[pw][cl][yrow] = p;
                // refill the freed slot with x_{t+5} (consumed at step t+4)
                const int tl = (t + 5 < TT) ? (t + 5) : (TT - 1);
                #pragma unroll
                for (int j = 0; j < 4; ++j) xsl[sl][j] = xbase[tl * tstr + roff[j]];
                LBAR();
            }
        }
    }
}

// ----------------------------------------------------------------
extern "C" void kernel_launch(void* const* d_in, const int* in_sizes, int n_in,
                              void* d_out, int out_size, void* d_ws, size_t ws_size,
                              hipStream_t stream) {
    const float* xs = (const float*)d_in[0];   // [32,256,128,64]
    const float* A  = (const float*)d_in[1];   // [32,128,128]
    float* out = (float*)d_out;                // [32,256,128,64]
    float* ws = (float*)d_ws;                  // needs 2 MB

    float* invMt = ws;                          // invM^T per batch [32][128][128]

    k_prep <<<BB, 256, 0, stream>>>(A, invMt);
    k_scan <<<BB * 4, 512, 0, stream>>>(invMt, xs, out);
}

// Round 9
// 277.759 us; speedup vs baseline: 4.0322x; 1.0354x over previous
//
#include <hip/hip_runtime.h>

#define BB 32
#define TT 256
#define NN 128
#define DD 64
#define KSTR 136   // dL column stride in halves: 272B -> 16B-aligned b128 frags

typedef _Float16 f16x4 __attribute__((ext_vector_type(4)));
typedef _Float16 f16x8 __attribute__((ext_vector_type(8)));
typedef float    f32x4v __attribute__((ext_vector_type(4)));

#define FMA4(acc, s, v) do { \
    acc.x = __builtin_fmaf((s), (v).x, acc.x); \
    acc.y = __builtin_fmaf((s), (v).y, acc.y); \
    acc.z = __builtin_fmaf((s), (v).z, acc.z); \
    acc.w = __builtin_fmaf((s), (v).w, acc.w); } while (0)

// barrier that drains only LDS (lgkmcnt) — keeps global prefetch loads / stores in flight
#define LBAR() do { asm volatile("s_waitcnt lgkmcnt(0)" ::: "memory"); \
                    __builtin_amdgcn_s_barrier(); } while (0)

// ---------------------------------------------------------------- K1: fused build + blocked GJ inverse -> invM^T
// Phase 1 (panel GJ) now carries the panel in REGISTERS: thread (rg,jl) owns
// v[8] = rows rg*8..+8 of panel col jl. Per ministep only the pivot column
// (fcol, published by jl==kl threads) and pivot-row entries (akj) pass through
// double-buffered LDS scratch -> 1 barrier + 4 LDS reads per ministep
// (was 2 barriers + 18 scattered b32 reads). Formulas identical to r5-r8.
__global__ __launch_bounds__(256) void k_prep(const float* __restrict__ A,
                                              float* __restrict__ invMt) {
    __shared__ __align__(16) float sM[NN][132];   // 67.5 KB
    __shared__ __align__(16) float rB[16][NN];    // 8 KB; rB[0] hosts deg first
    __shared__ float fcol[2][NN];                 // pivot-column scratch (dbuf)
    __shared__ float akj[2][16];                  // pivot-row-entry scratch (dbuf)
    const int b = blockIdx.x;
    const int tid = threadIdx.x;
    const float* Ab = A + b * NN * NN;

    if (tid < NN) {
        float s = 0.f;
        const float4* A4 = (const float4*)(Ab + tid * NN);
        #pragma unroll 4
        for (int j = 0; j < NN / 4; ++j) { float4 v = A4[j]; s += v.x + v.y + v.z + v.w; }
        rB[0][tid] = s;
    }
    __syncthreads();
    for (int flat = tid; flat < NN * NN; flat += 256) {
        const int i = flat >> 7, j = flat & 127;
        const float a = Ab[flat];
        sM[i][j] = -a + ((i == j) ? (rB[0][i] + 1.1f) : 0.f);
    }
    __syncthreads();

    const int jl = tid & 15;     // panel column (phase 1)
    const int rg = tid >> 4;     // row group: rows rg*8..rg*8+8 (phase 1)
    const int qq = tid & 31;     // column quad (phase 2)
    const int rh = tid >> 5;     // row half-set (phase 2)

    for (int pk = 0; pk < 8; ++pk) {
        const int K0 = pk << 4;

        // ---- phase 1: register-carried panel GJ
        float v[8];
        #pragma unroll
        for (int r = 0; r < 8; ++r) v[r] = sM[rg * 8 + r][K0 + jl];

        for (int kl = 0; kl < 16; ++kl) {
            const int k = K0 + kl;
            const int buf = kl & 1;
            if (jl == kl) {                       // publish current pivot column
                #pragma unroll
                for (int r = 0; r < 8; ++r) fcol[buf][rg * 8 + r] = v[r];
            }
            if (rg == (k >> 3)) {                 // publish pivot-row entry for col jl
                float pick = v[0];
                #pragma unroll
                for (int r = 1; r < 8; ++r) if ((k & 7) == r) pick = v[r];
                akj[buf][jl] = pick;
            }
            __syncthreads();
            const float pv = akj[buf][kl];        // pivot value (broadcast)
            const float a  = akj[buf][jl];        // pivot row, this thread's col
            float fc[8];
            #pragma unroll
            for (int r = 0; r < 8; ++r) fc[r] = fcol[buf][rg * 8 + r];
            const float p  = 1.0f / pv;
            const float ap = a * p;
            #pragma unroll
            for (int r = 0; r < 8; ++r) {
                const int i = rg * 8 + r;
                float nv;
                if (jl == kl) nv = (i == k) ? p  : -fc[r] * p;
                else          nv = (i == k) ? ap : v[r] - fc[r] * ap;
                v[r] = nv;
            }
            // dbuf scratch: publish(kl+1) writes buf^1; reads(kl) of buf are
            // separated from publish(kl+2) by sync(kl+1). one barrier/ministep.
        }
        // write the new panel back
        #pragma unroll
        for (int r = 0; r < 8; ++r) sM[rg * 8 + r][K0 + jl] = v[r];
        __syncthreads();

        // ---- stage old row-block R = sM[K0..K0+16)[all cols]
        // (panel cols of rB are post-phase1 values, but phase 2 never reads them)
        for (int q = tid; q < 16 * NN / 4; q += 256) {
            const int m = q >> 5, j4 = (q & 31) << 2;
            *(float4*)&rB[m][j4] = *(float4*)&sM[K0 + m][j4];
        }
        __syncthreads();

        // ---- phase 2: rank-16 update of non-panel columns
        const int pq0 = K0 >> 2;
        const bool act = (qq < pq0) || (qq >= pq0 + 4);
        float4 Rq[16];
        if (act) {
            #pragma unroll
            for (int m = 0; m < 16; ++m) Rq[m] = *(float4*)&rB[m][qq << 2];
        }
        #pragma unroll 2
        for (int r = 0; r < 16; ++r) {
            const int i = rh * 16 + r;
            float4 c0 = *(float4*)&sM[i][K0];
            float4 c1 = *(float4*)&sM[i][K0 + 4];
            float4 c2 = *(float4*)&sM[i][K0 + 8];
            float4 c3 = *(float4*)&sM[i][K0 + 12];
            if (act) {
                const bool prow = (i >= K0) && (i < K0 + 16);
                float4 acc;
                if (prow) { acc.x = acc.y = acc.z = acc.w = 0.f; }
                else        acc = *(float4*)&sM[i][qq << 2];
                FMA4(acc, c0.x, Rq[0]);  FMA4(acc, c0.y, Rq[1]);
                FMA4(acc, c0.z, Rq[2]);  FMA4(acc, c0.w, Rq[3]);
                FMA4(acc, c1.x, Rq[4]);  FMA4(acc, c1.y, Rq[5]);
                FMA4(acc, c1.z, Rq[6]);  FMA4(acc, c1.w, Rq[7]);
                FMA4(acc, c2.x, Rq[8]);  FMA4(acc, c2.y, Rq[9]);
                FMA4(acc, c2.z, Rq[10]); FMA4(acc, c2.w, Rq[11]);
                FMA4(acc, c3.x, Rq[12]); FMA4(acc, c3.y, Rq[13]);
                FMA4(acc, c3.z, Rq[14]); FMA4(acc, c3.w, Rq[15]);
                *(float4*)&sM[i][qq << 2] = acc;
            }
        }
        __syncthreads();
    }
    // write transposed: invMt[k][i] = invM[i][k]
    for (int flat = tid; flat < NN * NN; flat += 256) {
        const int kk = flat >> 7, ii = flat & 127;
        invMt[b * NN * NN + flat] = sM[ii][kk];
    }
}

// ---------------------------------------------------------------- K2: collapsed scan, 256 blocks (all CUs)
// y_t = y_{t-1} + invM*(x_t - y_{t-1}); y in fp32 registers; d fp16 via dbuf LDS.
// Each block: (batch b, 8-col chunk dc). 8 waves (2/SIMD), wave w owns rows
// [16w,16w+16). MFMA B-operand: lanes cl>=8 duplicate col cl-8 (their output
// cols are garbage and never stored -> columns independent, harmless).
// Per-CU HBM traffic halves vs r8 (8 KB/step); 256 CUs active.
__global__ __launch_bounds__(512, 1) void k_scan(const float* __restrict__ invMt,
                                                 const float* __restrict__ xs,
                                                 float* __restrict__ out) {
    __shared__ __align__(16) _Float16 dL[2][8][KSTR];

    const int bid = blockIdx.x;
    const int xcd = bid & 7, g = bid >> 3;
    const int dc = g & 7, b = (xcd << 2) | (g >> 3);   // 8 dc-siblings of a batch share an XCD
    const int tid = threadIdx.x;
    const int w = tid >> 6, l = tid & 63;
    const int cl = l & 15;       // MFMA col slot; real col = dc*8 + (cl&7)
    const int h = l >> 4;        // k-subgroup (0..3) / D-row-group
    const bool io = (cl < 8);    // lanes that own a real column (load/store/publish)

    // ---- preload invM A-frags (rows R = 16w+cl), hi/lo split; kappa(h,e)=8h+e
    f16x8 VHi[4], VLo[4];
    {
        const float* Vb = invMt + b * NN * NN;
        const int R = w * 16 + cl;
        #pragma unroll
        for (int ks = 0; ks < 4; ++ks) {
            #pragma unroll
            for (int e = 0; e < 8; ++e) {
                const int k = ks * 32 + h * 8 + e;
                float gv = Vb[k * NN + R];              // invMt[k][R] = invM[R][k]
                _Float16 gh = (_Float16)gv;
                VHi[ks][e] = gh;
                VLo[ks][e] = (_Float16)((gv - (float)gh) * 4096.0f);
            }
        }
    }

    const int tstr = NN * DD;
    const size_t base = (size_t)b * TT * tstr + dc * 8 + (cl & 7);
    const float* xbase = xs + base;
    float* obase = out + base;
    int roff[4];
    #pragma unroll
    for (int j = 0; j < 4; ++j)
        roff[j] = (w * 16 + h * 4 + j) * DD;   // D-layout rows of this lane
    const int yrow = w * 16 + h * 4;

    float y[4] = {0.f, 0.f, 0.f, 0.f};
    float xsl[4][4];   // slot s holds x_{t'} with t' ≡ s (mod 4); static indexing only

    // ---- prologue: d_0 = x_0 (y_{-1}=0); fill slots with x_1..x_4
    {
        float x0r[4] = {0.f, 0.f, 0.f, 0.f};
        if (io) {
            #pragma unroll
            for (int j = 0; j < 4; ++j) x0r[j] = xbase[roff[j]];
            #pragma unroll
            for (int j = 0; j < 4; ++j) xsl[1][j] = xbase[1 * tstr + roff[j]];
            #pragma unroll
            for (int j = 0; j < 4; ++j) xsl[2][j] = xbase[2 * tstr + roff[j]];
            #pragma unroll
            for (int j = 0; j < 4; ++j) xsl[3][j] = xbase[3 * tstr + roff[j]];
            #pragma unroll
            for (int j = 0; j < 4; ++j) xsl[0][j] = xbase[4 * tstr + roff[j]];
            f16x4 p;
            #pragma unroll
            for (int j = 0; j < 4; ++j) p[j] = (_Float16)x0r[j];
            *(f16x4*)&dL[0][cl][yrow] = p;
        }
        LBAR();   // d_0 visible
    }

    // ---- main loop: step t reads dL[t&1], publishes d_{t+1} into dL[(t+1)&1]
    for (int i = 0; i < TT / 4; ++i) {
        #pragma unroll
        for (int u = 0; u < 4; ++u) {
            const int t = 4 * i + u;
            const int pr = u & 1, pw = pr ^ 1;   // t&1 == u&1 (4i even)
            const int sl = (u + 1) & 3;          // slot holding x_{t+1}

            // m = invM * d_t  (hi/lo chains, depth 4, independent)
            f32x4v mH = {0.f,0.f,0.f,0.f}, mL = {0.f,0.f,0.f,0.f};
            #pragma unroll
            for (int ks = 0; ks < 4; ++ks) {
                f16x8 bf = *(const f16x8*)&dL[pr][cl & 7][ks * 32 + h * 8];
                mH = __builtin_amdgcn_mfma_f32_16x16x32_f16(VHi[ks], bf, mH, 0, 0, 0);
                mL = __builtin_amdgcn_mfma_f32_16x16x32_f16(VLo[ks], bf, mL, 0, 0, 0);
            }
            #pragma unroll
            for (int j = 0; j < 4; ++j)
                y[j] += __builtin_fmaf(mL[j], 1.0f / 4096.0f, mH[j]);

            // store y_t (fire-and-forget; barriers never drain vmcnt)
            if (io) {
                #pragma unroll
                for (int j = 0; j < 4; ++j) obase[t * tstr + roff[j]] = y[j];
            }

            if (u != 3 || i != TT / 4 - 1) {     // all but the very last step
                if (io) {
                    // publish d_{t+1} = x_{t+1} - y_t
                    f16x4 p;
                    #pragma unroll
                    for (int j = 0; j < 4; ++j) p[j] = (_Float16)(xsl[sl][j] - y[j]);
                    *(f16x4*)&dL[pw][cl][yrow] = p;
                    // refill the freed slot with x_{t+5} (consumed at step t+4)
                    const int tl = (t + 5 < TT) ? (t + 5) : (TT - 1);
                    #pragma unroll
                    for (int j = 0; j < 4; ++j) xsl[sl][j] = xbase[tl * tstr + roff[j]];
                }
                LBAR();
            }
        }
    }
}

// ----------------------------------------------------------------
extern "C" void kernel_launch(void* const* d_in, const int* in_sizes, int n_in,
                              void* d_out, int out_size, void* d_ws, size_t ws_size,
                              hipStream_t stream) {
    const float* xs = (const float*)d_in[0];   // [32,256,128,64]
    const float* A  = (const float*)d_in[1];   // [32,128,128]
    float* out = (float*)d_out;                // [32,256,128,64]
    float* ws = (float*)d_ws;                  // needs 2 MB

    float* invMt = ws;                          // invM^T per batch [32][128][128]

    k_prep <<<BB, 256, 0, stream>>>(A, invMt);
    k_scan <<<BB * 8, 512, 0, stream>>>(invMt, xs, out);
}

// Round 10
// 271.934 us; speedup vs baseline: 4.1186x; 1.0214x over previous
//
#include <hip/hip_runtime.h>

#define BB 32
#define TT 256
#define NN 128
#define DD 64
#define KSTR 136   // dL column stride in halves: 272B -> 16B-aligned b128 frags

typedef _Float16 f16x4 __attribute__((ext_vector_type(4)));
typedef _Float16 f16x8 __attribute__((ext_vector_type(8)));
typedef float    f32x4v __attribute__((ext_vector_type(4)));

#define FMA4(acc, s, v) do { \
    acc.x = __builtin_fmaf((s), (v).x, acc.x); \
    acc.y = __builtin_fmaf((s), (v).y, acc.y); \
    acc.z = __builtin_fmaf((s), (v).z, acc.z); \
    acc.w = __builtin_fmaf((s), (v).w, acc.w); } while (0)

// barrier that drains only LDS (lgkmcnt) — keeps global loads / stores in flight
#define LBAR() do { asm volatile("s_waitcnt lgkmcnt(0)" ::: "memory"); \
                    __builtin_amdgcn_s_barrier(); } while (0)

// async global->LDS: wave-uniform LDS base, HW adds lane*16; global addr per-lane
__device__ __forceinline__ void gl_lds16(const float* g, void* l) {
    __builtin_amdgcn_global_load_lds((const __attribute__((address_space(1))) void*)g,
                                     (__attribute__((address_space(3))) void*)l, 16, 0, 0);
}

// ---------------------------------------------------------------- K1: fused build + blocked GJ inverse -> invM^T
// (validated r8/r9 structure, unchanged)
__global__ __launch_bounds__(256) void k_prep(const float* __restrict__ A,
                                              float* __restrict__ invMt) {
    __shared__ __align__(16) float sM[NN][132];   // 67.5 KB
    __shared__ __align__(16) float rB[16][NN];    // 8 KB; rB[0] hosts deg first
    __shared__ float fcol[2][NN];                 // pivot-column scratch (dbuf)
    __shared__ float akj[2][16];                  // pivot-row-entry scratch (dbuf)
    const int b = blockIdx.x;
    const int tid = threadIdx.x;
    const float* Ab = A + b * NN * NN;

    if (tid < NN) {
        float s = 0.f;
        const float4* A4 = (const float4*)(Ab + tid * NN);
        #pragma unroll 4
        for (int j = 0; j < NN / 4; ++j) { float4 v = A4[j]; s += v.x + v.y + v.z + v.w; }
        rB[0][tid] = s;
    }
    __syncthreads();
    for (int flat = tid; flat < NN * NN; flat += 256) {
        const int i = flat >> 7, j = flat & 127;
        const float a = Ab[flat];
        sM[i][j] = -a + ((i == j) ? (rB[0][i] + 1.1f) : 0.f);
    }
    __syncthreads();

    const int jl = tid & 15;     // panel column (phase 1)
    const int rg = tid >> 4;     // row group: rows rg*8..rg*8+8 (phase 1)
    const int qq = tid & 31;     // column quad (phase 2)
    const int rh = tid >> 5;     // row half-set (phase 2)

    for (int pk = 0; pk < 8; ++pk) {
        const int K0 = pk << 4;

        // ---- phase 1: register-carried panel GJ
        float v[8];
        #pragma unroll
        for (int r = 0; r < 8; ++r) v[r] = sM[rg * 8 + r][K0 + jl];

        for (int kl = 0; kl < 16; ++kl) {
            const int k = K0 + kl;
            const int buf = kl & 1;
            if (jl == kl) {                       // publish current pivot column
                #pragma unroll
                for (int r = 0; r < 8; ++r) fcol[buf][rg * 8 + r] = v[r];
            }
            if (rg == (k >> 3)) {                 // publish pivot-row entry for col jl
                float pick = v[0];
                #pragma unroll
                for (int r = 1; r < 8; ++r) if ((k & 7) == r) pick = v[r];
                akj[buf][jl] = pick;
            }
            __syncthreads();
            const float pv = akj[buf][kl];        // pivot value (broadcast)
            const float a  = akj[buf][jl];        // pivot row, this thread's col
            float fc[8];
            #pragma unroll
            for (int r = 0; r < 8; ++r) fc[r] = fcol[buf][rg * 8 + r];
            const float p  = 1.0f / pv;
            const float ap = a * p;
            #pragma unroll
            for (int r = 0; r < 8; ++r) {
                const int i = rg * 8 + r;
                float nv;
                if (jl == kl) nv = (i == k) ? p  : -fc[r] * p;
                else          nv = (i == k) ? ap : v[r] - fc[r] * ap;
                v[r] = nv;
            }
        }
        #pragma unroll
        for (int r = 0; r < 8; ++r) sM[rg * 8 + r][K0 + jl] = v[r];
        __syncthreads();

        // ---- stage old row-block R = sM[K0..K0+16)[all cols]
        for (int q = tid; q < 16 * NN / 4; q += 256) {
            const int m = q >> 5, j4 = (q & 31) << 2;
            *(float4*)&rB[m][j4] = *(float4*)&sM[K0 + m][j4];
        }
        __syncthreads();

        // ---- phase 2: rank-16 update of non-panel columns
        const int pq0 = K0 >> 2;
        const bool act = (qq < pq0) || (qq >= pq0 + 4);
        float4 Rq[16];
        if (act) {
            #pragma unroll
            for (int m = 0; m < 16; ++m) Rq[m] = *(float4*)&rB[m][qq << 2];
        }
        #pragma unroll 2
        for (int r = 0; r < 16; ++r) {
            const int i = rh * 16 + r;
            float4 c0 = *(float4*)&sM[i][K0];
            float4 c1 = *(float4*)&sM[i][K0 + 4];
            float4 c2 = *(float4*)&sM[i][K0 + 8];
            float4 c3 = *(float4*)&sM[i][K0 + 12];
            if (act) {
                const bool prow = (i >= K0) && (i < K0 + 16);
                float4 acc;
                if (prow) { acc.x = acc.y = acc.z = acc.w = 0.f; }
                else        acc = *(float4*)&sM[i][qq << 2];
                FMA4(acc, c0.x, Rq[0]);  FMA4(acc, c0.y, Rq[1]);
                FMA4(acc, c0.z, Rq[2]);  FMA4(acc, c0.w, Rq[3]);
                FMA4(acc, c1.x, Rq[4]);  FMA4(acc, c1.y, Rq[5]);
                FMA4(acc, c1.z, Rq[6]);  FMA4(acc, c1.w, Rq[7]);
                FMA4(acc, c2.x, Rq[8]);  FMA4(acc, c2.y, Rq[9]);
                FMA4(acc, c2.z, Rq[10]); FMA4(acc, c2.w, Rq[11]);
                FMA4(acc, c3.x, Rq[12]); FMA4(acc, c3.y, Rq[13]);
                FMA4(acc, c3.z, Rq[14]); FMA4(acc, c3.w, Rq[15]);
                *(float4*)&sM[i][qq << 2] = acc;
            }
        }
        __syncthreads();
    }
    // write transposed: invMt[k][i] = invM[i][k]
    for (int flat = tid; flat < NN * NN; flat += 256) {
        const int kk = flat >> 7, ii = flat & 127;
        invMt[b * NN * NN + flat] = sM[ii][kk];
    }
}

// ---------------------------------------------------------------- K2: collapsed scan, LDS-decoupled memory paths
// y_t = y_{t-1} + invM*(x_t - y_{t-1}); y in fp32 registers; d fp16 via dbuf dL.
// x path: even waves issue ONE global_load_lds_dwordx4 per step into a 4-slot
//   LDS ring xS (4 steps ahead). Publish reads x from LDS -> NO compiler vmcnt
//   at the consume; only a hand vmcnt(4) (2-step slack) on even waves.
// y path: y written to yS (scalar, off-path), then after the existing barrier
//   one ds_read_b128 + global_store_dwordx4 per lane (4x fewer store requests).
// One barrier per step (lgkm only); stores/loads never drained at barriers.
__global__ __launch_bounds__(512, 1) void k_scan(const float* __restrict__ invMt,
                                                 const float* __restrict__ xs,
                                                 float* __restrict__ out) {
    __shared__ __align__(16) _Float16 dL[2][8][KSTR];   // 4.25 KB
    __shared__ __align__(16) float xS[4][NN][8];        // 16 KB, linear (gload dest)
    __shared__ __align__(16) float yS[NN][8];           // 4 KB

    const int bid = blockIdx.x;
    const int xcd = bid & 7, g = bid >> 3;
    const int dc = g & 7, b = (xcd << 2) | (g >> 3);   // dc-siblings share an XCD
    const int tid = threadIdx.x;
    const int w = tid >> 6, l = tid & 63;
    const int cl = l & 15;       // MFMA col slot; real col = dc*8 + (cl&7)
    const int h = l >> 4;        // k-subgroup (0..3) / D-row-group
    const bool io = (cl < 8);    // lanes that own a real column
    const bool evw = ((w & 1) == 0);

    // ---- preload invM A-frags (rows R = 16w+cl), hi/lo split; kappa(h,e)=8h+e
    f16x8 VHi[4], VLo[4];
    {
        const float* Vb = invMt + b * NN * NN;
        const int R = w * 16 + cl;
        #pragma unroll
        for (int ks = 0; ks < 4; ++ks) {
            #pragma unroll
            for (int e = 0; e < 8; ++e) {
                const int k = ks * 32 + h * 8 + e;
                float gv = Vb[k * NN + R];              // invMt[k][R] = invM[R][k]
                _Float16 gh = (_Float16)gv;
                VHi[ks][e] = gh;
                VLo[ks][e] = (_Float16)((gv - (float)gh) * 4096.0f);
            }
        }
    }

    const int tstr = NN * DD;
    const size_t gb = (size_t)b * TT * tstr + dc * 8;
    const float* xg = xs + gb;
    float* og = out + gb;
    // load/store lane map: row = 16w + (l>>1), col quad = 4*(l&1)
    const int lrow = w * 16 + (l >> 1);
    const int lq4 = 4 * (l & 1);
    const int yrow = w * 16 + h * 4;

    float y[4] = {0.f, 0.f, 0.f, 0.f};

    // ---- prologue
    // (A) x_0 -> xS[0]
    if (evw) gl_lds16(xg + (size_t)lrow * DD + lq4, &xS[0][w * 16][0]);
    if (evw) asm volatile("s_waitcnt vmcnt(0)" ::: "memory");
    LBAR();
    // (B) publish d_0 = x_0
    {
        f16x4 p;
        #pragma unroll
        for (int j = 0; j < 4; ++j) p[j] = (_Float16)xS[0][w * 16 + 4 * h + j][cl & 7];
        if (io) *(f16x4*)&dL[0][cl][yrow] = p;
    }
    LBAR();   // d_0 visible; xS[0] reads complete before any overwrite
    // (C) x_1..x_3 -> slots 1..3  (step 0 will load x_4 -> slot 0)
    if (evw) {
        gl_lds16(xg + 1 * tstr + (size_t)lrow * DD + lq4, &xS[1][w * 16][0]);
        gl_lds16(xg + 2 * tstr + (size_t)lrow * DD + lq4, &xS[2][w * 16][0]);
        gl_lds16(xg + 3 * tstr + (size_t)lrow * DD + lq4, &xS[3][w * 16][0]);
        asm volatile("s_waitcnt vmcnt(0)" ::: "memory");
    }
    LBAR();

    // ---- main loop. Invariant at step t: dL[t&1]=d_t; xS slots hold x_{t+1..t+4}
    for (int i = 0; i < TT / 4; ++i) {
        #pragma unroll
        for (int u = 0; u < 4; ++u) {
            const int t = 4 * i + u;
            const int pr = u & 1, pw = pr ^ 1;

            // phase 0: store y_{t-1} from yS (coalesced float4; fire-and-forget)
            if (t > 0 && l < 32) {
                float4 v = *(const float4*)&yS[lrow][lq4];
                *(float4*)(og + (size_t)(t - 1) * tstr + (size_t)lrow * DD + lq4) = v;
            }

            // phase 1: x for publish (LDS ring) — independent of y
            float xp[4];
            #pragma unroll
            for (int j = 0; j < 4; ++j)
                xp[j] = xS[(u + 1) & 3][w * 16 + 4 * h + j][cl & 7];

            // phase 2: m = invM * d_t  (hi/lo chains, depth 4)
            f32x4v mH = {0.f,0.f,0.f,0.f}, mL = {0.f,0.f,0.f,0.f};
            #pragma unroll
            for (int ks = 0; ks < 4; ++ks) {
                f16x8 bf = *(const f16x8*)&dL[pr][cl & 7][ks * 32 + h * 8];
                mH = __builtin_amdgcn_mfma_f32_16x16x32_f16(VHi[ks], bf, mH, 0, 0, 0);
                mL = __builtin_amdgcn_mfma_f32_16x16x32_f16(VLo[ks], bf, mL, 0, 0, 0);
            }
            #pragma unroll
            for (int j = 0; j < 4; ++j)
                y[j] += __builtin_fmaf(mL[j], 1.0f / 4096.0f, mH[j]);

            // phase 3: publish d_{t+1} = x_{t+1} - y_t ; stage y_t for next-step store
            if (io) {
                f16x4 p;
                #pragma unroll
                for (int j = 0; j < 4; ++j) p[j] = (_Float16)(xp[j] - y[j]);
                *(f16x4*)&dL[pw][cl][yrow] = p;
                #pragma unroll
                for (int j = 0; j < 4; ++j) yS[w * 16 + 4 * h + j][cl & 7] = y[j];
            }

            // phase 4: issue x_{t+4} -> slot t&3 (its old content consumed at t-1)
            {
                const int tl = (t + 4 < TT) ? (t + 4) : (TT - 1);
                if (evw) gl_lds16(xg + (size_t)tl * tstr + (size_t)lrow * DD + lq4,
                                  &xS[u][w * 16][0]);
            }

            // phase 5: even waves bound outstanding vmem (2-step slack; never stalls)
            if (evw) asm volatile("s_waitcnt vmcnt(4)" ::: "memory");

            // phase 6
            LBAR();
        }
    }

    // epilogue: store y_{TT-1} (final LBAR already drained yS writes)
    if (l < 32) {
        float4 v = *(const float4*)&yS[lrow][lq4];
        *(float4*)(og + (size_t)(TT - 1) * tstr + (size_t)lrow * DD + lq4) = v;
    }
}

// ----------------------------------------------------------------
extern "C" void kernel_launch(void* const* d_in, const int* in_sizes, int n_in,
                              void* d_out, int out_size, void* d_ws, size_t ws_size,
                              hipStream_t stream) {
    const float* xs = (const float*)d_in[0];   // [32,256,128,64]
    const float* A  = (const float*)d_in[1];   // [32,128,128]
    float* out = (float*)d_out;                // [32,256,128,64]
    float* ws = (float*)d_ws;                  // needs 2 MB

    float* invMt = ws;                          // invM^T per batch [32][128][128]

    k_prep <<<BB, 256, 0, stream>>>(A, invMt);
    k_scan <<<BB * 8, 512, 0, stream>>>(invMt, xs, out);
}